// Round 2
// 901.210 us; speedup vs baseline: 1.4717x; 1.4717x over previous
//
#include <hip/hip_runtime.h>
#include <math.h>

#define B 64
#define T 512
#define H 768
#define DOUT 192
#define MTEXT (B*T)        // 32768
#define MSPEC (B*8)        // 512

typedef unsigned short u16;
typedef __attribute__((ext_vector_type(8))) short short8;
typedef __attribute__((ext_vector_type(4))) short s4v;
typedef __attribute__((ext_vector_type(4))) float floatx4;

__device__ __forceinline__ float bf2f(u16 u){
  union { float f; unsigned int i; } v; v.i = ((unsigned int)u) << 16; return v.f;
}
__device__ __forceinline__ u16 f2bf(float f){
  unsigned int u = __float_as_uint(f);
  unsigned int lsb = (u >> 16) & 1u;
  u += 0x7fffu + lsb;
  return (u16)(u >> 16);
}
__device__ __forceinline__ float lrelu(float v){ return v > 0.f ? v : 0.2f*v; }
__device__ __forceinline__ float ldv(const void* p, size_t i, int isF32){
  return isF32 ? ((const float*)p)[i] : bf2f(((const u16*)p)[i]);
}

// ---------------- detect input dtype ----------------
__global__ __launch_bounds__(256) void detect_kernel(const u16* __restrict__ raw, int* __restrict__ flag){
  __shared__ int red[256];
  int tid = threadIdx.x;
  int cnt = 0;
  for (int i = tid; i < 2048; i += 256){
    u16 u = raw[(size_t)i*2];
    int e = (u >> 7) & 0xFF;
    if (e >= 110 && e <= 135) cnt++;
  }
  red[tid] = cnt; __syncthreads();
  for (int s = 128; s > 0; s >>= 1){ if (tid < s) red[tid] += red[tid+s]; __syncthreads(); }
  if (tid == 0) *flag = (red[0] < 1024) ? 1 : 0;   // 1 => float32 inputs
}

// ---------------- convert raw param (f32 or bf16) -> bf16 ----------------
__global__ __launch_bounds__(256) void convert_kernel(const void* __restrict__ src,
                                                      u16* __restrict__ dst, int n,
                                                      const int* __restrict__ flagp){
  int i = blockIdx.x*256 + threadIdx.x;
  if (i >= n) return;
  if (*flagp) dst[i] = f2bf(((const float*)src)[i]);
  else        dst[i] = ((const u16*)src)[i];
}

// ---------------- prep specials: label/image -> xs (bf16) + sq-norms ----------------
__global__ __launch_bounds__(256) void prep_spec_kernel(const void* __restrict__ label,
                                                        const void* __restrict__ image,
                                                        u16* __restrict__ xs,
                                                        float* __restrict__ norms2,
                                                        const int* __restrict__ flagp){
  __shared__ float red[256];
  int isF32 = *flagp;
  int rr = blockIdx.x;          // 0..511
  int tid = threadIdx.x;
  int b = rr >> 3, s = rr & 7;
  const void* srcb = (s < 4) ? label : image;
  size_t base = (size_t)(b*4 + (s & 3))*H;
  float sq = 0.f;
  #pragma unroll
  for (int r = 0; r < 3; r++){
    int dd = tid + r*256;
    float f = ldv(srcb, base + dd, isF32);
    xs[(size_t)rr*H + dd] = f2bf(f);
    sq += f*f;
  }
  red[tid] = sq; __syncthreads();
  for (int ss = 128; ss > 0; ss >>= 1){ if (tid < ss) red[tid] += red[tid+ss]; __syncthreads(); }
  if (tid == 0) norms2[rr] = red[0];
}

// ---------------- topk: excluded (argmin) label/image index per (b,t) ----------------
__global__ __launch_bounds__(64) void topk_kernel(const void* __restrict__ text,
                                                  const void* __restrict__ label,
                                                  const void* __restrict__ image,
                                                  const float* __restrict__ norms2,
                                                  int* __restrict__ excl_l,
                                                  int* __restrict__ excl_i,
                                                  const int* __restrict__ flagp){
  int isF32 = *flagp;
  int t = blockIdx.x, b = blockIdx.y;
  int lane = threadIdx.x;
  float dl[4] = {0,0,0,0}, di[4] = {0,0,0,0};
  size_t tbase = (size_t)(b*T + t)*H;
  for (int r = 0; r < 12; r++){
    int d = lane + r*64;
    float tx = ldv(text, tbase + d, isF32);
    #pragma unroll
    for (int j = 0; j < 4; j++){
      dl[j] += tx * ldv(label, (size_t)(b*4 + j)*H + d, isF32);
      di[j] += tx * ldv(image, (size_t)(b*4 + j)*H + d, isF32);
    }
  }
  #pragma unroll
  for (int j = 0; j < 4; j++){
    for (int o = 32; o > 0; o >>= 1){
      dl[j] += __shfl_down(dl[j], o);
      di[j] += __shfl_down(di[j], o);
    }
  }
  if (lane == 0){
    float vl[4], vi[4];
    #pragma unroll
    for (int j = 0; j < 4; j++){
      vl[j] = dl[j] / fmaxf(sqrtf(norms2[b*8 + j]), 1e-8f);
      vi[j] = di[j] / fmaxf(sqrtf(norms2[b*8 + 4 + j]), 1e-8f);
    }
    int el = 0, ei = 0;
    #pragma unroll
    for (int j = 1; j < 4; j++){
      if (vl[j] <= vl[el]) el = j;
      if (vi[j] <= vi[ei]) ei = j;
    }
    excl_l[b*T + t] = el;
    excl_i[b*T + t] = ei;
  }
}

// ---------------- GEMM: h[hrows,768](bf16) = x @ W^T ----------------
__global__ __launch_bounds__(256) void gemm_kernel(const void* __restrict__ At, int arow0,
                                                   const u16* __restrict__ As,
                                                   const u16* __restrict__ Bw,
                                                   u16* __restrict__ C,
                                                   int text_tiles, int ctext,
                                                   const int* __restrict__ flagp){
  __shared__ __align__(16) u16 lA[128*72];
  __shared__ __align__(16) u16 lB[128*72];
  int isF32 = *flagp;
  int tid = threadIdx.x;
  int tile = blockIdx.x;
  bool spec = (tile >= text_tiles);
  int lrow0 = spec ? (tile - text_tiles)*128 : tile*128;
  int crow0 = spec ? (ctext + lrow0) : lrow0;
  const u16*   Abf = spec ? (As + (size_t)lrow0*H)
                          : ((const u16*)At + (size_t)(arow0 + lrow0)*H);
  const float* Af  = (const float*)At + (size_t)(arow0 + lrow0)*H;
  int nbase = blockIdx.y * 128;
  int wave = tid >> 6, lane = tid & 63;
  int wm = (wave >> 1) * 64, wn = (wave & 1) * 64;
  int lrow = lane & 15, lkq = (lane >> 4) * 8;
  int r0 = tid >> 3;
  int c0 = (tid & 7) * 8;

  floatx4 acc[4][4];
  #pragma unroll
  for (int i = 0; i < 4; i++)
    #pragma unroll
    for (int j = 0; j < 4; j++)
      acc[i][j] = (floatx4){0.f,0.f,0.f,0.f};

  for (int k0 = 0; k0 < H; k0 += 64){
    short8 va[4], vb[4];
    #pragma unroll
    for (int i = 0; i < 4; i++){
      int row = i*32 + r0;
      if (spec || !isF32) va[i] = *(const short8*)(Abf + (size_t)row*H + k0 + c0);
      else {
        const float* p = Af + (size_t)row*H + k0 + c0;
        float4 lo = *(const float4*)p;
        float4 hi = *(const float4*)(p + 4);
        short8 tv;
        tv[0]=(short)f2bf(lo.x); tv[1]=(short)f2bf(lo.y); tv[2]=(short)f2bf(lo.z); tv[3]=(short)f2bf(lo.w);
        tv[4]=(short)f2bf(hi.x); tv[5]=(short)f2bf(hi.y); tv[6]=(short)f2bf(hi.z); tv[7]=(short)f2bf(hi.w);
        va[i] = tv;
      }
      vb[i] = *(const short8*)(Bw + (size_t)(nbase + row)*H + k0 + c0);
    }
    __syncthreads();
    #pragma unroll
    for (int i = 0; i < 4; i++){
      int row = i*32 + r0;
      *(short8*)(lA + row*72 + c0) = va[i];
      *(short8*)(lB + row*72 + c0) = vb[i];
    }
    __syncthreads();
    #pragma unroll
    for (int kk = 0; kk < 2; kk++){
      short8 af[4], bfv[4];
      #pragma unroll
      for (int i = 0; i < 4; i++){
        af[i]  = *(const short8*)(lA + (wm + i*16 + lrow)*72 + kk*32 + lkq);
        bfv[i] = *(const short8*)(lB + (wn + i*16 + lrow)*72 + kk*32 + lkq);
      }
      #pragma unroll
      for (int i = 0; i < 4; i++)
        #pragma unroll
        for (int j = 0; j < 4; j++)
          acc[i][j] = __builtin_amdgcn_mfma_f32_16x16x32_bf16(af[i], bfv[j], acc[i][j], 0, 0, 0);
    }
  }
  int qrow = (lane >> 4) * 4;
  int col = lane & 15;
  #pragma unroll
  for (int i = 0; i < 4; i++)
    #pragma unroll
    for (int j = 0; j < 4; j++)
      #pragma unroll
      for (int r = 0; r < 4; r++){
        int grow = crow0 + wm + i*16 + qrow + r;
        int gcol = nbase + wn + j*16 + col;
        C[(size_t)grow*H + gcol] = f2bf(acc[i][j][r]);
      }
}

// ---------------- per-node es/ed: block per node, vectorized short4 loads ----------------
__global__ __launch_bounds__(256) void node_att_kernel(const u16* __restrict__ h,
                                                       const u16* __restrict__ a_s,
                                                       const u16* __restrict__ a_d,
                                                       float* __restrict__ es,
                                                       float* __restrict__ ed){
  int node = blockIdx.x;
  int head = threadIdx.x >> 6, lane = threadIdx.x & 63;
  float s = 0.f, d = 0.f;
  if (lane < 48){
    s4v hv = *(const s4v*)(h   + (size_t)node*H + head*DOUT + lane*4);
    s4v sv = *(const s4v*)(a_s + head*DOUT + lane*4);
    s4v dv = *(const s4v*)(a_d + head*DOUT + lane*4);
    #pragma unroll
    for (int c = 0; c < 4; c++){
      float hf = bf2f((u16)hv[c]);
      s += hf * bf2f((u16)sv[c]);
      d += hf * bf2f((u16)dv[c]);
    }
  }
  #pragma unroll
  for (int o = 32; o > 0; o >>= 1){ s += __shfl_down(s, o); d += __shfl_down(d, o); }
  if (lane == 0){ es[node*4 + head] = s; ed[node*4 + head] = d; }
}

// ---------------- fused attention: specials first, then text (wave-per-node) ----------------
__global__ __launch_bounds__(256) void attn_kernel(
    const u16* __restrict__ h,
    const void* __restrict__ xprev, int xrow0, void* __restrict__ xout,
    u16* __restrict__ xs_c,
    const float* __restrict__ es, const float* __restrict__ ed,
    const int* __restrict__ exl_c, const int* __restrict__ exi_c,
    const u16* __restrict__ bias, const u16* __restrict__ gamma, const u16* __restrict__ beta,
    int ctext, int cspec, const int* __restrict__ flagp){
  __shared__ float wred[16];
  __shared__ float alpha_l[4][9][4];
  __shared__ float wdyn[512][4];
  __shared__ float sw[8][4];
  __shared__ float wm4[4][4], wsum4[4][4];

  int isF32 = *flagp;
  int tid = threadIdx.x, wave = tid >> 6, lane = tid & 63;

  if ((int)blockIdx.x >= cspec){
    // ================= text destinations: 4 nodes per block, one wave each =================
    int loc = (blockIdx.x - cspec)*4 + wave;
    int bloc = loc >> 9, t = loc & 511;
    int el = exl_c[loc], ei = exi_c[loc];
    int sbase = ctext + bloc*8;

    // wave-parallel softmax: lane = e*4 + hh (36 active lanes).
    // source-node id computed arithmetically per lane (no runtime-indexed
    // local array -> stays in VGPRs, rule #20)
    int e = lane >> 2, hh = lane & 3;
    bool act = (e < 9) && !(e == 1 && t == 0) && !(e == 2 && t == T-1);
    int srcE;
    if (e == 0)      srcE = loc;
    else if (e == 1) srcE = loc - 1;
    else if (e == 2) srcE = loc + 1;
    else if (e < 6){ int k = e - 3; srcE = sbase + k + (k >= el ? 1 : 0); }
    else           { int k = e - 6; srcE = sbase + 4 + (k & 3) + ((k & 3) >= ei ? 1 : 0); }
    float v = -1e30f;
    if (act) v = lrelu(es[srcE*4 + hh] + ed[loc*4 + hh]);
    float m = v;
    #pragma unroll
    for (int o = 4; o < 64; o <<= 1) m = fmaxf(m, __shfl_xor(m, o));
    float w = act ? expf(fminf(v - m, 0.f)) : 0.f;
    float den = w;
    #pragma unroll
    for (int o = 4; o < 64; o <<= 1) den += __shfl_xor(den, o);
    if (e < 9) alpha_l[wave][e][hh] = w / (den + 1e-16f);
    __syncthreads();

    // source ids for the aggregation (compile-time indexed only)
    int srcs[9];
    srcs[0] = loc;
    srcs[1] = (t > 0)   ? loc - 1 : loc;   // dummy self if boundary (alpha forced 0)
    srcs[2] = (t < T-1) ? loc + 1 : loc;
    #pragma unroll
    for (int k = 0; k < 3; k++){
      srcs[3+k] = sbase + k + (k >= el ? 1 : 0);       // 3 selected labels
      srcs[6+k] = sbase + 4 + k + (k >= ei ? 1 : 0);   // 3 selected images
    }

    // aggregation: lane owns 3 chunks of 4 contiguous dims (d0, d0+256, d0+512)
    int d0 = lane*4;
    int hk0 = d0/DOUT, hk1 = (d0+256)/DOUT, hk2 = (d0+512)/DOUT;
    float a0[4] = {0,0,0,0}, a1[4] = {0,0,0,0}, a2[4] = {0,0,0,0};
    #pragma unroll
    for (int ee = 0; ee < 9; ee++){
      const u16* hp = h + (size_t)srcs[ee]*H + d0;
      s4v v0 = *(const s4v*)(hp);
      s4v v1 = *(const s4v*)(hp + 256);
      s4v v2 = *(const s4v*)(hp + 512);
      float al0 = alpha_l[wave][ee][hk0];
      float al1 = alpha_l[wave][ee][hk1];
      float al2 = alpha_l[wave][ee][hk2];
      #pragma unroll
      for (int c = 0; c < 4; c++){
        a0[c] += al0 * bf2f((u16)v0[c]);
        a1[c] += al1 * bf2f((u16)v1[c]);
        a2[c] += al2 * bf2f((u16)v2[c]);
      }
    }

    // bias + relu + residual + LN stats (in-wave butterfly, no LDS)
    size_t xoff = (size_t)(xrow0 + loc)*H + d0;
    s4v b0 = *(const s4v*)(bias + d0);
    s4v b1 = *(const s4v*)(bias + d0 + 256);
    s4v b2 = *(const s4v*)(bias + d0 + 512);
    float xr0[4], xr1[4], xr2[4];
    if (isF32){
      const float* xp = (const float*)xprev + xoff;
      float4 x0 = *(const float4*)xp;
      float4 x1 = *(const float4*)(xp + 256);
      float4 x2 = *(const float4*)(xp + 512);
      xr0[0]=x0.x; xr0[1]=x0.y; xr0[2]=x0.z; xr0[3]=x0.w;
      xr1[0]=x1.x; xr1[1]=x1.y; xr1[2]=x1.z; xr1[3]=x1.w;
      xr2[0]=x2.x; xr2[1]=x2.y; xr2[2]=x2.z; xr2[3]=x2.w;
    } else {
      const u16* xp = (const u16*)xprev + xoff;
      s4v x0 = *(const s4v*)xp;
      s4v x1 = *(const s4v*)(xp + 256);
      s4v x2 = *(const s4v*)(xp + 512);
      #pragma unroll
      for (int c = 0; c < 4; c++){
        xr0[c] = bf2f((u16)x0[c]); xr1[c] = bf2f((u16)x1[c]); xr2[c] = bf2f((u16)x2[c]);
      }
    }
    float y0[4], y1[4], y2[4];
    float sum = 0.f, sumsq = 0.f;
    #pragma unroll
    for (int c = 0; c < 4; c++){
      y0[c] = fmaxf(a0[c] + bf2f((u16)b0[c]), 0.f) + xr0[c];
      y1[c] = fmaxf(a1[c] + bf2f((u16)b1[c]), 0.f) + xr1[c];
      y2[c] = fmaxf(a2[c] + bf2f((u16)b2[c]), 0.f) + xr2[c];
      sum   += y0[c] + y1[c] + y2[c];
      sumsq += y0[c]*y0[c] + y1[c]*y1[c] + y2[c]*y2[c];
    }
    #pragma unroll
    for (int o = 1; o < 64; o <<= 1){
      sum   += __shfl_xor(sum, o);
      sumsq += __shfl_xor(sumsq, o);
    }
    float mean = sum * (1.f/H);
    float var = sumsq * (1.f/H) - mean*mean;
    float rstd = rsqrtf(fmaxf(var, 0.f) + 1e-5f);
    s4v g0 = *(const s4v*)(gamma + d0);
    s4v g1 = *(const s4v*)(gamma + d0 + 256);
    s4v g2 = *(const s4v*)(gamma + d0 + 512);
    s4v be0 = *(const s4v*)(beta + d0);
    s4v be1 = *(const s4v*)(beta + d0 + 256);
    s4v be2 = *(const s4v*)(beta + d0 + 512);
    float o0[4], o1[4], o2[4];
    #pragma unroll
    for (int c = 0; c < 4; c++){
      o0[c] = (y0[c] - mean) * rstd * bf2f((u16)g0[c]) + bf2f((u16)be0[c]);
      o1[c] = (y1[c] - mean) * rstd * bf2f((u16)g1[c]) + bf2f((u16)be1[c]);
      o2[c] = (y2[c] - mean) * rstd * bf2f((u16)g2[c]) + bf2f((u16)be2[c]);
    }
    if (isF32){
      float* xo = (float*)xout + xoff;
      float4 w0, w1, w2;
      w0.x=o0[0]; w0.y=o0[1]; w0.z=o0[2]; w0.w=o0[3];
      w1.x=o1[0]; w1.y=o1[1]; w1.z=o1[2]; w1.w=o1[3];
      w2.x=o2[0]; w2.y=o2[1]; w2.z=o2[2]; w2.w=o2[3];
      *(float4*)xo = w0; *(float4*)(xo + 256) = w1; *(float4*)(xo + 512) = w2;
    } else {
      u16* xo = (u16*)xout + xoff;
      s4v w0, w1, w2;
      #pragma unroll
      for (int c = 0; c < 4; c++){
        w0[c] = (short)f2bf(o0[c]); w1[c] = (short)f2bf(o1[c]); w2[c] = (short)f2bf(o2[c]);
      }
      *(s4v*)xo = w0; *(s4v*)(xo + 256) = w1; *(s4v*)(xo + 512) = w2;
    }
  } else {
    // ================= special destination =================
    int idx = blockIdx.x;
    int bloc = idx >> 3, s = idx & 7;
    int node = ctext + idx;
    const int* excl = (s < 4) ? exl_c : exi_c;
    int target = s & 3;
    float edv[4];
    #pragma unroll
    for (int hh = 0; hh < 4; hh++) edv[hh] = ed[node*4 + hh];

    int t0 = tid, t1 = tid + 256;
    bool sel0 = (excl[bloc*512 + t0] != target);
    bool sel1 = (excl[bloc*512 + t1] != target);
    const float* e0 = es + (size_t)(bloc*512 + t0)*4;
    const float* e1 = es + (size_t)(bloc*512 + t1)*4;
    float v0[4], v1[4], vs[4], m[4];
    #pragma unroll
    for (int hh = 0; hh < 4; hh++){
      v0[hh] = sel0 ? lrelu(e0[hh] + edv[hh]) : -1e30f;
      v1[hh] = sel1 ? lrelu(e1[hh] + edv[hh]) : -1e30f;
      m[hh] = fmaxf(v0[hh], v1[hh]);
    }
    if (tid < 8){
      const float* ep = es + (size_t)(ctext + bloc*8 + tid)*4;
      #pragma unroll
      for (int hh = 0; hh < 4; hh++){ vs[hh] = lrelu(ep[hh] + edv[hh]); m[hh] = fmaxf(m[hh], vs[hh]); }
    }
    #pragma unroll
    for (int hh = 0; hh < 4; hh++)
      for (int o = 32; o > 0; o >>= 1) m[hh] = fmaxf(m[hh], __shfl_down(m[hh], o));
    if (lane == 0){
      #pragma unroll
      for (int hh = 0; hh < 4; hh++) wm4[wave][hh] = m[hh];
    }
    __syncthreads();
    #pragma unroll
    for (int hh = 0; hh < 4; hh++)
      m[hh] = fmaxf(fmaxf(wm4[0][hh], wm4[1][hh]), fmaxf(wm4[2][hh], wm4[3][hh]));

    float ds[4];
    #pragma unroll
    for (int hh = 0; hh < 4; hh++){
      float w0 = sel0 ? expf(fminf(v0[hh] - m[hh], 0.f)) : 0.f;
      float w1 = sel1 ? expf(fminf(v1[hh] - m[hh], 0.f)) : 0.f;
      wdyn[t0][hh] = w0; wdyn[t1][hh] = w1;
      ds[hh] = w0 + w1;
    }
    if (tid < 8){
      #pragma unroll
      for (int hh = 0; hh < 4; hh++){
        float w = expf(fminf(vs[hh] - m[hh], 0.f));
        sw[tid][hh] = w; ds[hh] += w;
      }
    }
    #pragma unroll
    for (int hh = 0; hh < 4; hh++)
      for (int o = 32; o > 0; o >>= 1) ds[hh] += __shfl_down(ds[hh], o);
    if (lane == 0){
      #pragma unroll
      for (int hh = 0; hh < 4; hh++) wsum4[wave][hh] = ds[hh];
    }
    __syncthreads();   // also makes wdyn/sw visible

    // aggregation: thread cc<192 owns 4 contiguous dims, vectorized short4 loads
    int cc = tid;
    int hh4 = (cc < 192) ? (cc/48) : 0;
    float dinv = 1.f / (wsum4[0][hh4] + wsum4[1][hh4] + wsum4[2][hh4] + wsum4[3][hh4] + 1e-16f);
    float agg[4] = {0.f, 0.f, 0.f, 0.f};
    if (cc < 192){
      const u16* hp = h + (size_t)(bloc*512)*H + cc*4;
      #pragma unroll 8
      for (int tt = 0; tt < 512; tt++){
        s4v hv = *(const s4v*)(hp + (size_t)tt*H);
        float wv = wdyn[tt][hh4];
        agg[0] += wv * bf2f((u16)hv[0]);
        agg[1] += wv * bf2f((u16)hv[1]);
        agg[2] += wv * bf2f((u16)hv[2]);
        agg[3] += wv * bf2f((u16)hv[3]);
      }
      #pragma unroll
      for (int e2 = 0; e2 < 8; e2++){
        s4v hv = *(const s4v*)(h + (size_t)(ctext + bloc*8 + e2)*H + cc*4);
        float wv = sw[e2][hh4];
        agg[0] += wv * bf2f((u16)hv[0]);
        agg[1] += wv * bf2f((u16)hv[1]);
        agg[2] += wv * bf2f((u16)hv[2]);
        agg[3] += wv * bf2f((u16)hv[3]);
      }
    }
    float y[4] = {0.f,0.f,0.f,0.f};
    float sum = 0.f, sumsq = 0.f;
    if (cc < 192){
      s4v bv = *(const s4v*)(bias + cc*4);
      s4v xv = *(const s4v*)(xs_c + (size_t)idx*H + cc*4);
      #pragma unroll
      for (int c = 0; c < 4; c++){
        float a = agg[c] * dinv;
        float o = fmaxf(a + bf2f((u16)bv[c]), 0.f);
        float yv = o + bf2f((u16)xv[c]);
        y[c] = yv; sum += yv; sumsq += yv*yv;
      }
    }
    for (int o = 32; o > 0; o >>= 1){ sum += __shfl_down(sum, o); sumsq += __shfl_down(sumsq, o); }
    if (lane == 0){ wred[wave] = sum; wred[8 + wave] = sumsq; }
    __syncthreads();
    sum   = wred[0] + wred[1] + wred[2] + wred[3];
    sumsq = wred[8] + wred[9] + wred[10] + wred[11];
    float mean = sum * (1.f/H);
    float var = sumsq * (1.f/H) - mean*mean;
    float rstd = rsqrtf(fmaxf(var, 0.f) + 1e-5f);
    if (cc < 192){
      s4v gv = *(const s4v*)(gamma + cc*4);
      s4v bev = *(const s4v*)(beta + cc*4);
      s4v wv;
      #pragma unroll
      for (int c = 0; c < 4; c++){
        float o = (y[c] - mean) * rstd * bf2f((u16)gv[c]) + bf2f((u16)bev[c]);
        wv[c] = (short)f2bf(o);
      }
      *(s4v*)(xs_c + (size_t)idx*H + cc*4) = wv;
    }
  }
}

extern "C" void kernel_launch(void* const* d_in, const int* in_sizes, int n_in,
                              void* d_out, int out_size, void* d_ws, size_t ws_size,
                              hipStream_t stream){
  const void* text  = d_in[0];
  const void* label = d_in[1];
  const void* image = d_in[2];

  auto align256 = [](size_t x){ return (x + 255) & ~(size_t)255; };

  // pick chunk count from ws_size (deterministic -> graph-safe)
  int nch = 8, ctext = MTEXT/8, cspec = MSPEC/8, spec_tiles = 1, hrows = 0;
  for (int cand = 1; cand <= 8; cand <<= 1){
    int ct = MTEXT/cand, cs = MSPEC/cand;
    int st = (cs + 127)/128;
    int hr = ct + st*128;
    size_t need = align256(4)
                + align256((size_t)hr*H*2)
                + align256((size_t)(MSPEC+64)*H*2)
                + 2*align256((size_t)MTEXT*4)
                + align256((size_t)MSPEC*4)
                + 2*align256((size_t)hr*4*4)
                + align256((size_t)3*H*H*2)
                + 5*align256((size_t)3*H*2);
    if (need <= ws_size || cand == 8){
      nch = cand; ctext = ct; cspec = cs; spec_tiles = st; hrows = hr;
      break;
    }
  }
  int text_tiles = ctext / 128;

  char* ws = (char*)d_ws;
  size_t off = 0;
  auto alloc = [&](size_t bytes) -> void* {
    void* p = ws + off; off += (bytes + 255) & ~(size_t)255; return p;
  };
  int*   flag = (int*)  alloc(4);
  u16*   h    = (u16*)  alloc((size_t)hrows*H*2);
  u16*   xs   = (u16*)  alloc((size_t)(MSPEC+64)*H*2);
  int*   exl  = (int*)  alloc((size_t)MTEXT*4);
  int*   exi  = (int*)  alloc((size_t)MTEXT*4);
  float* nrm  = (float*)alloc((size_t)MSPEC*4);
  float* es   = (float*)alloc((size_t)hrows*4*4);
  float* ed   = (float*)alloc((size_t)hrows*4*4);
  u16*   Wc   = (u16*)  alloc((size_t)3*H*H*2);
  u16*   asc  = (u16*)  alloc((size_t)3*H*2);
  u16*   adc  = (u16*)  alloc((size_t)3*H*2);
  u16*   bc   = (u16*)  alloc((size_t)3*H*2);
  u16*   gc   = (u16*)  alloc((size_t)3*H*2);
  u16*   bec  = (u16*)  alloc((size_t)3*H*2);

  detect_kernel<<<1, 256, 0, stream>>>((const u16*)text, flag);
  convert_kernel<<<(3*H*H + 255)/256, 256, 0, stream>>>(d_in[3], Wc, 3*H*H, flag);
  convert_kernel<<<9, 256, 0, stream>>>(d_in[4], asc, 3*H, flag);
  convert_kernel<<<9, 256, 0, stream>>>(d_in[5], adc, 3*H, flag);
  convert_kernel<<<9, 256, 0, stream>>>(d_in[6], bc,  3*H, flag);
  convert_kernel<<<9, 256, 0, stream>>>(d_in[7], gc,  3*H, flag);
  convert_kernel<<<9, 256, 0, stream>>>(d_in[8], bec, 3*H, flag);

  prep_spec_kernel<<<MSPEC, 256, 0, stream>>>(label, image, xs, nrm, flag);
  topk_kernel<<<dim3(T, B), 64, 0, stream>>>(text, label, image, nrm, exl, exi, flag);

  for (int l = 0; l < 3; l++){
    const void* xprev = (l == 0) ? text : (const void*)d_out;
    for (int c = 0; c < nch; c++){
      gemm_kernel<<<dim3(text_tiles + spec_tiles, 6), 256, 0, stream>>>(
          xprev, c*ctext, xs + (size_t)c*cspec*H, Wc + (size_t)l*H*H, h,
          text_tiles, ctext, flag);
      node_att_kernel<<<ctext + cspec, 256, 0, stream>>>(
          h, asc + l*H, adc + l*H, es, ed);
      attn_kernel<<<cspec + ctext/4, 256, 0, stream>>>(
          h, xprev, c*ctext, d_out, xs + (size_t)c*cspec*H,
          es, ed, exl + c*ctext, exi + c*ctext,
          bc + l*H, gc + l*H, bec + l*H,
          ctext, cspec, flag);
    }
  }
}

// Round 3
// 891.283 us; speedup vs baseline: 1.4881x; 1.0111x over previous
//
#include <hip/hip_runtime.h>
#include <math.h>

#define B 64
#define T 512
#define H 768
#define DOUT 192
#define MTEXT (B*T)        // 32768
#define MSPEC (B*8)        // 512

typedef unsigned short u16;
typedef __attribute__((ext_vector_type(8))) short short8;
typedef __attribute__((ext_vector_type(4))) short s4v;
typedef __attribute__((ext_vector_type(4))) float floatx4;

__device__ __forceinline__ float bf2f(u16 u){
  union { float f; unsigned int i; } v; v.i = ((unsigned int)u) << 16; return v.f;
}
__device__ __forceinline__ u16 f2bf(float f){
  unsigned int u = __float_as_uint(f);
  unsigned int lsb = (u >> 16) & 1u;
  u += 0x7fffu + lsb;
  return (u16)(u >> 16);
}
__device__ __forceinline__ float lrelu(float v){ return v > 0.f ? v : 0.2f*v; }
__device__ __forceinline__ float ldv(const void* p, size_t i, int isF32){
  return isF32 ? ((const float*)p)[i] : bf2f(((const u16*)p)[i]);
}

// ---------------- detect input dtype ----------------
__global__ __launch_bounds__(256) void detect_kernel(const u16* __restrict__ raw, int* __restrict__ flag){
  __shared__ int red[256];
  int tid = threadIdx.x;
  int cnt = 0;
  for (int i = tid; i < 2048; i += 256){
    u16 u = raw[(size_t)i*2];
    int e = (u >> 7) & 0xFF;
    if (e >= 110 && e <= 135) cnt++;
  }
  red[tid] = cnt; __syncthreads();
  for (int s = 128; s > 0; s >>= 1){ if (tid < s) red[tid] += red[tid+s]; __syncthreads(); }
  if (tid == 0) *flag = (red[0] < 1024) ? 1 : 0;   // 1 => float32 inputs
}

// ---------------- convert raw param (f32 or bf16) -> bf16 ----------------
__global__ __launch_bounds__(256) void convert_kernel(const void* __restrict__ src,
                                                      u16* __restrict__ dst, int n,
                                                      const int* __restrict__ flagp){
  int i = blockIdx.x*256 + threadIdx.x;
  if (i >= n) return;
  if (*flagp) dst[i] = f2bf(((const float*)src)[i]);
  else        dst[i] = ((const u16*)src)[i];
}

// ---------------- convert text -> bf16 (vectorized, 4 elems/thread) ----------------
__global__ __launch_bounds__(256) void convert_text_kernel(const void* __restrict__ src,
                                                           u16* __restrict__ dst,
                                                           const int* __restrict__ flagp){
  size_t i = (size_t)blockIdx.x*256 + threadIdx.x;   // one group of 4 elems
  if (*flagp){
    float4 v = ((const float4*)src)[i];
    s4v o;
    o[0] = (short)f2bf(v.x); o[1] = (short)f2bf(v.y);
    o[2] = (short)f2bf(v.z); o[3] = (short)f2bf(v.w);
    ((s4v*)dst)[i] = o;
  } else {
    ((s4v*)dst)[i] = ((const s4v*)src)[i];
  }
}

// ---------------- prep specials: label/image -> xs (bf16) + sq-norms ----------------
__global__ __launch_bounds__(256) void prep_spec_kernel(const void* __restrict__ label,
                                                        const void* __restrict__ image,
                                                        u16* __restrict__ xs,
                                                        float* __restrict__ norms2,
                                                        const int* __restrict__ flagp){
  __shared__ float red[256];
  int isF32 = *flagp;
  int rr = blockIdx.x;          // 0..511
  int tid = threadIdx.x;
  int b = rr >> 3, s = rr & 7;
  const void* srcb = (s < 4) ? label : image;
  size_t base = (size_t)(b*4 + (s & 3))*H;
  float sq = 0.f;
  #pragma unroll
  for (int r = 0; r < 3; r++){
    int dd = tid + r*256;
    float f = ldv(srcb, base + dd, isF32);
    xs[(size_t)rr*H + dd] = f2bf(f);
    sq += f*f;
  }
  red[tid] = sq; __syncthreads();
  for (int ss = 128; ss > 0; ss >>= 1){ if (tid < ss) red[tid] += red[tid+ss]; __syncthreads(); }
  if (tid == 0) norms2[rr] = red[0];
}

// ---------------- topk: excluded (argmin) label/image index per (b,t) ----------------
__global__ __launch_bounds__(64) void topk_kernel(const void* __restrict__ text,
                                                  const void* __restrict__ label,
                                                  const void* __restrict__ image,
                                                  const float* __restrict__ norms2,
                                                  int* __restrict__ excl_l,
                                                  int* __restrict__ excl_i,
                                                  const int* __restrict__ flagp){
  int isF32 = *flagp;
  int t = blockIdx.x, b = blockIdx.y;
  int lane = threadIdx.x;
  float dl[4] = {0,0,0,0}, di[4] = {0,0,0,0};
  size_t tbase = (size_t)(b*T + t)*H;
  for (int r = 0; r < 12; r++){
    int d = lane + r*64;
    float tx = ldv(text, tbase + d, isF32);
    #pragma unroll
    for (int j = 0; j < 4; j++){
      dl[j] += tx * ldv(label, (size_t)(b*4 + j)*H + d, isF32);
      di[j] += tx * ldv(image, (size_t)(b*4 + j)*H + d, isF32);
    }
  }
  #pragma unroll
  for (int j = 0; j < 4; j++){
    for (int o = 32; o > 0; o >>= 1){
      dl[j] += __shfl_down(dl[j], o);
      di[j] += __shfl_down(di[j], o);
    }
  }
  if (lane == 0){
    float vl[4], vi[4];
    #pragma unroll
    for (int j = 0; j < 4; j++){
      vl[j] = dl[j] / fmaxf(sqrtf(norms2[b*8 + j]), 1e-8f);
      vi[j] = di[j] / fmaxf(sqrtf(norms2[b*8 + 4 + j]), 1e-8f);
    }
    int el = 0, ei = 0;
    #pragma unroll
    for (int j = 1; j < 4; j++){
      if (vl[j] <= vl[el]) el = j;
      if (vi[j] <= vi[ei]) ei = j;
    }
    excl_l[b*T + t] = el;
    excl_i[b*T + t] = ei;
  }
}

// ---------------- GEMM: h[hrows,768](bf16) = x @ W^T ----------------
__global__ __launch_bounds__(256) void gemm_kernel(const void* __restrict__ At, int arow0,
                                                   const u16* __restrict__ As,
                                                   const u16* __restrict__ Bw,
                                                   u16* __restrict__ C,
                                                   int text_tiles, int ctext,
                                                   int forceBf,
                                                   const int* __restrict__ flagp){
  __shared__ __align__(16) u16 lA[128*72];
  __shared__ __align__(16) u16 lB[128*72];
  int isF32 = forceBf ? 0 : *flagp;
  int tid = threadIdx.x;

  // 1-D grid, XCD-aware bijective swizzle so the 6 col-tiles sharing an
  // A-panel (consecutive logical ids) land on the same XCD's L2.
  int nb = gridDim.x;
  int bid = blockIdx.x;
  int q = nb >> 3, r = nb & 7;
  int xcd = bid & 7, ixx = bid >> 3;
  int lid = (xcd < r ? xcd*(q+1) : r*(q+1) + (xcd - r)*q) + ixx;
  int tile = lid / 6;
  int nbase = (lid % 6) * 128;

  bool spec = (tile >= text_tiles);
  int lrow0 = spec ? (tile - text_tiles)*128 : tile*128;
  int crow0 = spec ? (ctext + lrow0) : lrow0;
  const u16*   Abf = spec ? (As + (size_t)lrow0*H)
                          : ((const u16*)At + (size_t)(arow0 + lrow0)*H);
  const float* Af  = (const float*)At + (size_t)(arow0 + lrow0)*H;
  int wave = tid >> 6, lane = tid & 63;
  int wm = (wave >> 1) * 64, wn = (wave & 1) * 64;
  int lrow = lane & 15, lkq = (lane >> 4) * 8;
  int r0 = tid >> 3;
  int c0 = (tid & 7) * 8;

  floatx4 acc[4][4];
  #pragma unroll
  for (int i = 0; i < 4; i++)
    #pragma unroll
    for (int j = 0; j < 4; j++)
      acc[i][j] = (floatx4){0.f,0.f,0.f,0.f};

  for (int k0 = 0; k0 < H; k0 += 64){
    short8 va[4], vb[4];
    #pragma unroll
    for (int i = 0; i < 4; i++){
      int row = i*32 + r0;
      if (spec || !isF32) va[i] = *(const short8*)(Abf + (size_t)row*H + k0 + c0);
      else {
        const float* p = Af + (size_t)row*H + k0 + c0;
        float4 lo = *(const float4*)p;
        float4 hi = *(const float4*)(p + 4);
        short8 tv;
        tv[0]=(short)f2bf(lo.x); tv[1]=(short)f2bf(lo.y); tv[2]=(short)f2bf(lo.z); tv[3]=(short)f2bf(lo.w);
        tv[4]=(short)f2bf(hi.x); tv[5]=(short)f2bf(hi.y); tv[6]=(short)f2bf(hi.z); tv[7]=(short)f2bf(hi.w);
        va[i] = tv;
      }
      vb[i] = *(const short8*)(Bw + (size_t)(nbase + row)*H + k0 + c0);
    }
    __syncthreads();
    #pragma unroll
    for (int i = 0; i < 4; i++){
      int row = i*32 + r0;
      *(short8*)(lA + row*72 + c0) = va[i];
      *(short8*)(lB + row*72 + c0) = vb[i];
    }
    __syncthreads();
    #pragma unroll
    for (int kk = 0; kk < 2; kk++){
      short8 af[4], bfv[4];
      #pragma unroll
      for (int i = 0; i < 4; i++){
        af[i]  = *(const short8*)(lA + (wm + i*16 + lrow)*72 + kk*32 + lkq);
        bfv[i] = *(const short8*)(lB + (wn + i*16 + lrow)*72 + kk*32 + lkq);
      }
      #pragma unroll
      for (int i = 0; i < 4; i++)
        #pragma unroll
        for (int j = 0; j < 4; j++)
          acc[i][j] = __builtin_amdgcn_mfma_f32_16x16x32_bf16(af[i], bfv[j], acc[i][j], 0, 0, 0);
    }
  }
  int qrow = (lane >> 4) * 4;
  int col = lane & 15;
  #pragma unroll
  for (int i = 0; i < 4; i++)
    #pragma unroll
    for (int j = 0; j < 4; j++)
      #pragma unroll
      for (int r2 = 0; r2 < 4; r2++){
        int grow = crow0 + wm + i*16 + qrow + r2;
        int gcol = nbase + wn + j*16 + col;
        C[(size_t)grow*H + gcol] = f2bf(acc[i][j][r2]);
      }
}

// ---------------- per-node es/ed: block per node, vectorized short4 loads ----------------
__global__ __launch_bounds__(256) void node_att_kernel(const u16* __restrict__ h,
                                                       const u16* __restrict__ a_s,
                                                       const u16* __restrict__ a_d,
                                                       float* __restrict__ es,
                                                       float* __restrict__ ed){
  int node = blockIdx.x;
  int head = threadIdx.x >> 6, lane = threadIdx.x & 63;
  float s = 0.f, d = 0.f;
  if (lane < 48){
    s4v hv = *(const s4v*)(h   + (size_t)node*H + head*DOUT + lane*4);
    s4v sv = *(const s4v*)(a_s + head*DOUT + lane*4);
    s4v dv = *(const s4v*)(a_d + head*DOUT + lane*4);
    #pragma unroll
    for (int c = 0; c < 4; c++){
      float hf = bf2f((u16)hv[c]);
      s += hf * bf2f((u16)sv[c]);
      d += hf * bf2f((u16)dv[c]);
    }
  }
  #pragma unroll
  for (int o = 32; o > 0; o >>= 1){ s += __shfl_down(s, o); d += __shfl_down(d, o); }
  if (lane == 0){ es[node*4 + head] = s; ed[node*4 + head] = d; }
}

// ---------------- attention, text destinations (wave-per-node, XCD swizzle) ----------------
__global__ __launch_bounds__(256) void attn_text_kernel(
    const u16* __restrict__ h,
    const u16* __restrict__ xres,        // bf16 residual source (when resBf)
    const void* __restrict__ xraw,       // raw residual source (when !resBf)
    int xrow0,
    void* __restrict__ xout,             // d_out (when outRaw)
    u16* __restrict__ xoutbf,            // xint (when !outRaw)
    const float* __restrict__ es, const float* __restrict__ ed,
    const int* __restrict__ exl_c, const int* __restrict__ exi_c,
    const u16* __restrict__ bias, const u16* __restrict__ gamma, const u16* __restrict__ beta,
    int ctext, int resBf, int outRaw, const int* __restrict__ flagp){
  __shared__ float alpha_l[4][9][4];

  int isF32 = *flagp;
  int tid = threadIdx.x, wave = tid >> 6, lane = tid & 63;

  // XCD-aware bijective swizzle (contiguous logical chunk per XCD)
  int nb = gridDim.x;
  int bid = blockIdx.x;
  int q = nb >> 3, r = nb & 7;
  int xcd = bid & 7, ixx = bid >> 3;
  int lb = (xcd < r ? xcd*(q+1) : r*(q+1) + (xcd - r)*q) + ixx;

  int loc = lb*4 + wave;
  int bloc = loc >> 9, t = loc & 511;
  int el = exl_c[loc], ei = exi_c[loc];
  int sbase = ctext + bloc*8;

  // wave-parallel softmax: lane = e*4 + hh (36 active lanes)
  int e = lane >> 2, hh = lane & 3;
  bool act = (e < 9) && !(e == 1 && t == 0) && !(e == 2 && t == T-1);
  int srcE;
  if (e == 0)      srcE = loc;
  else if (e == 1) srcE = loc - 1;
  else if (e == 2) srcE = loc + 1;
  else if (e < 6){ int k = e - 3; srcE = sbase + k + (k >= el ? 1 : 0); }
  else           { int k = e - 6; srcE = sbase + 4 + (k & 3) + ((k & 3) >= ei ? 1 : 0); }
  float v = -1e30f;
  if (act) v = lrelu(es[srcE*4 + hh] + ed[loc*4 + hh]);
  float m = v;
  #pragma unroll
  for (int o = 4; o < 64; o <<= 1) m = fmaxf(m, __shfl_xor(m, o));
  float w = act ? expf(fminf(v - m, 0.f)) : 0.f;
  float den = w;
  #pragma unroll
  for (int o = 4; o < 64; o <<= 1) den += __shfl_xor(den, o);
  if (e < 9) alpha_l[wave][e][hh] = w / (den + 1e-16f);
  __syncthreads();

  // source ids (compile-time indexed only)
  int srcs[9];
  srcs[0] = loc;
  srcs[1] = (t > 0)   ? loc - 1 : loc;
  srcs[2] = (t < T-1) ? loc + 1 : loc;
  #pragma unroll
  for (int k = 0; k < 3; k++){
    srcs[3+k] = sbase + k + (k >= el ? 1 : 0);
    srcs[6+k] = sbase + 4 + k + (k >= ei ? 1 : 0);
  }

  // aggregation: lane owns 3 chunks of 4 contiguous dims
  int d0 = lane*4;
  int hk0 = d0/DOUT, hk1 = (d0+256)/DOUT, hk2 = (d0+512)/DOUT;
  float a0[4] = {0,0,0,0}, a1[4] = {0,0,0,0}, a2[4] = {0,0,0,0};
  #pragma unroll
  for (int ee = 0; ee < 9; ee++){
    const u16* hp = h + (size_t)srcs[ee]*H + d0;
    s4v v0 = *(const s4v*)(hp);
    s4v v1 = *(const s4v*)(hp + 256);
    s4v v2 = *(const s4v*)(hp + 512);
    float al0 = alpha_l[wave][ee][hk0];
    float al1 = alpha_l[wave][ee][hk1];
    float al2 = alpha_l[wave][ee][hk2];
    #pragma unroll
    for (int c = 0; c < 4; c++){
      a0[c] += al0 * bf2f((u16)v0[c]);
      a1[c] += al1 * bf2f((u16)v1[c]);
      a2[c] += al2 * bf2f((u16)v2[c]);
    }
  }

  // bias + relu + residual + LN (in-wave butterfly)
  size_t xoff = (size_t)(xrow0 + loc)*H + d0;
  s4v b0 = *(const s4v*)(bias + d0);
  s4v b1 = *(const s4v*)(bias + d0 + 256);
  s4v b2 = *(const s4v*)(bias + d0 + 512);
  float xr0[4], xr1[4], xr2[4];
  if (resBf){
    const u16* xp = xres + xoff;
    s4v x0 = *(const s4v*)xp;
    s4v x1 = *(const s4v*)(xp + 256);
    s4v x2 = *(const s4v*)(xp + 512);
    #pragma unroll
    for (int c = 0; c < 4; c++){
      xr0[c] = bf2f((u16)x0[c]); xr1[c] = bf2f((u16)x1[c]); xr2[c] = bf2f((u16)x2[c]);
    }
  } else if (isF32){
    const float* xp = (const float*)xraw + xoff;
    float4 x0 = *(const float4*)xp;
    float4 x1 = *(const float4*)(xp + 256);
    float4 x2 = *(const float4*)(xp + 512);
    xr0[0]=x0.x; xr0[1]=x0.y; xr0[2]=x0.z; xr0[3]=x0.w;
    xr1[0]=x1.x; xr1[1]=x1.y; xr1[2]=x1.z; xr1[3]=x1.w;
    xr2[0]=x2.x; xr2[1]=x2.y; xr2[2]=x2.z; xr2[3]=x2.w;
  } else {
    const u16* xp = (const u16*)xraw + xoff;
    s4v x0 = *(const s4v*)xp;
    s4v x1 = *(const s4v*)(xp + 256);
    s4v x2 = *(const s4v*)(xp + 512);
    #pragma unroll
    for (int c = 0; c < 4; c++){
      xr0[c] = bf2f((u16)x0[c]); xr1[c] = bf2f((u16)x1[c]); xr2[c] = bf2f((u16)x2[c]);
    }
  }
  float y0[4], y1[4], y2[4];
  float sum = 0.f, sumsq = 0.f;
  #pragma unroll
  for (int c = 0; c < 4; c++){
    y0[c] = fmaxf(a0[c] + bf2f((u16)b0[c]), 0.f) + xr0[c];
    y1[c] = fmaxf(a1[c] + bf2f((u16)b1[c]), 0.f) + xr1[c];
    y2[c] = fmaxf(a2[c] + bf2f((u16)b2[c]), 0.f) + xr2[c];
    sum   += y0[c] + y1[c] + y2[c];
    sumsq += y0[c]*y0[c] + y1[c]*y1[c] + y2[c]*y2[c];
  }
  #pragma unroll
  for (int o = 1; o < 64; o <<= 1){
    sum   += __shfl_xor(sum, o);
    sumsq += __shfl_xor(sumsq, o);
  }
  float mean = sum * (1.f/H);
  float var = sumsq * (1.f/H) - mean*mean;
  float rstd = rsqrtf(fmaxf(var, 0.f) + 1e-5f);
  s4v g0 = *(const s4v*)(gamma + d0);
  s4v g1 = *(const s4v*)(gamma + d0 + 256);
  s4v g2 = *(const s4v*)(gamma + d0 + 512);
  s4v be0 = *(const s4v*)(beta + d0);
  s4v be1 = *(const s4v*)(beta + d0 + 256);
  s4v be2 = *(const s4v*)(beta + d0 + 512);
  float o0[4], o1[4], o2[4];
  #pragma unroll
  for (int c = 0; c < 4; c++){
    o0[c] = (y0[c] - mean) * rstd * bf2f((u16)g0[c]) + bf2f((u16)be0[c]);
    o1[c] = (y1[c] - mean) * rstd * bf2f((u16)g1[c]) + bf2f((u16)be1[c]);
    o2[c] = (y2[c] - mean) * rstd * bf2f((u16)g2[c]) + bf2f((u16)be2[c]);
  }
  if (!outRaw){
    u16* xo = xoutbf + xoff;
    s4v w0, w1, w2;
    #pragma unroll
    for (int c = 0; c < 4; c++){
      w0[c] = (short)f2bf(o0[c]); w1[c] = (short)f2bf(o1[c]); w2[c] = (short)f2bf(o2[c]);
    }
    *(s4v*)xo = w0; *(s4v*)(xo + 256) = w1; *(s4v*)(xo + 512) = w2;
  } else if (isF32){
    float* xo = (float*)xout + xoff;
    float4 w0, w1, w2;
    w0.x=o0[0]; w0.y=o0[1]; w0.z=o0[2]; w0.w=o0[3];
    w1.x=o1[0]; w1.y=o1[1]; w1.z=o1[2]; w1.w=o1[3];
    w2.x=o2[0]; w2.y=o2[1]; w2.z=o2[2]; w2.w=o2[3];
    *(float4*)xo = w0; *(float4*)(xo + 256) = w1; *(float4*)(xo + 512) = w2;
  } else {
    u16* xo = (u16*)xout + xoff;
    s4v w0, w1, w2;
    #pragma unroll
    for (int c = 0; c < 4; c++){
      w0[c] = (short)f2bf(o0[c]); w1[c] = (short)f2bf(o1[c]); w2[c] = (short)f2bf(o2[c]);
    }
    *(s4v*)xo = w0; *(s4v*)(xo + 256) = w1; *(s4v*)(xo + 512) = w2;
  }
}

// ---------------- attention, special destinations: ONE block per batch, 8 specials ----------------
__global__ __launch_bounds__(256) void attn_spec_kernel(
    const u16* __restrict__ h, u16* __restrict__ xs_c,
    const float* __restrict__ es, const float* __restrict__ ed,
    const int* __restrict__ exl_c, const int* __restrict__ exi_c,
    const u16* __restrict__ bias, const u16* __restrict__ gamma, const u16* __restrict__ beta,
    int ctext){
  __shared__ float eds[8][4], ess[8][4], mm[8][4];
  __shared__ float red32[4][32];
  __shared__ float denT[8][4];
  __shared__ float swl[8][8][4];
  __shared__ float wl[256][32];     // weights chunk, XOR-swizzled: [row][(hh*8+s)^(row&31)]
  __shared__ float wred[16];

  int bloc = blockIdx.x;
  int tid = threadIdx.x, wave = tid >> 6, lane = tid & 63;
  int tbase = bloc*512;
  int sbase = ctext + bloc*8;

  if (tid < 32){
    int s = tid >> 2, hh = tid & 3;
    eds[s][hh] = ed[(size_t)(sbase + s)*4 + hh];
    ess[s][hh] = es[(size_t)(sbase + s)*4 + hh];
  }
  __syncthreads();

  // ---- phase 1: per-(s,hh) running max over included text rows ----
  float mx[8][4];
  #pragma unroll
  for (int s = 0; s < 8; s++)
    #pragma unroll
    for (int hh = 0; hh < 4; hh++) mx[s][hh] = -1e30f;
  #pragma unroll
  for (int rr = 0; rr < 2; rr++){
    int t = tbase + rr*256 + tid;
    float4 e4 = *(const float4*)(es + (size_t)t*4);
    int el = exl_c[t], ei = exi_c[t];
    float ev[4] = {e4.x, e4.y, e4.z, e4.w};
    #pragma unroll
    for (int s = 0; s < 8; s++){
      bool incl = (s < 4) ? (el != s) : (ei != s - 4);
      if (incl){
        #pragma unroll
        for (int hh = 0; hh < 4; hh++)
          mx[s][hh] = fmaxf(mx[s][hh], lrelu(ev[hh] + eds[s][hh]));
      }
    }
  }
  #pragma unroll
  for (int s = 0; s < 8; s++)
    #pragma unroll
    for (int hh = 0; hh < 4; hh++){
      float v = mx[s][hh];
      #pragma unroll
      for (int o = 32; o > 0; o >>= 1) v = fmaxf(v, __shfl_xor(v, o));
      mx[s][hh] = v;
    }
  if (lane == 0){
    #pragma unroll
    for (int s = 0; s < 8; s++)
      #pragma unroll
      for (int hh = 0; hh < 4; hh++) red32[wave][s*4 + hh] = mx[s][hh];
  }
  __syncthreads();
  if (tid < 32){
    int s = tid >> 2, hh = tid & 3;
    float v = fmaxf(fmaxf(red32[0][tid], red32[1][tid]), fmaxf(red32[2][tid], red32[3][tid]));
    #pragma unroll
    for (int e2 = 0; e2 < 8; e2++) v = fmaxf(v, lrelu(ess[e2][hh] + eds[s][hh]));
    mm[s][hh] = v;
  }
  __syncthreads();
  // special-source weights (all 8 specials are sources of each special)
  if (tid < 64){
    int s = tid >> 3, e2 = tid & 7;
    #pragma unroll
    for (int hh = 0; hh < 4; hh++)
      swl[s][e2][hh] = expf(fminf(lrelu(ess[e2][hh] + eds[s][hh]) - mm[s][hh], 0.f));
  }
  __syncthreads();

  // ---- phase 2: weights + denominators + aggregation (2 chunks of 256 rows) ----
  float den[8][4], agg[8][4];
  #pragma unroll
  for (int s = 0; s < 8; s++)
    #pragma unroll
    for (int c = 0; c < 4; c++){ den[s][c] = 0.f; agg[s][c] = 0.f; }

  int cc = tid;
  int hh4 = (tid < 192) ? (tid / 48) : 0;

  #pragma unroll
  for (int ch = 0; ch < 2; ch++){
    {
      int t = tbase + ch*256 + tid;
      float4 e4 = *(const float4*)(es + (size_t)t*4);
      int el = exl_c[t], ei = exi_c[t];
      float ev[4] = {e4.x, e4.y, e4.z, e4.w};
      #pragma unroll
      for (int s = 0; s < 8; s++){
        bool incl = (s < 4) ? (el != s) : (ei != s - 4);
        #pragma unroll
        for (int hh = 0; hh < 4; hh++){
          float w = incl ? expf(fminf(lrelu(ev[hh] + eds[s][hh]) - mm[s][hh], 0.f)) : 0.f;
          den[s][hh] += w;
          wl[tid][(hh*8 + s) ^ (tid & 31)] = w;
        }
      }
    }
    __syncthreads();
    if (tid < 192){
      const u16* hp = h + (size_t)(tbase + ch*256)*H + cc*4;
      #pragma unroll 4
      for (int t2 = 0; t2 < 256; t2++){
        s4v hv = *(const s4v*)(hp + (size_t)t2*H);
        float hf0 = bf2f((u16)hv[0]), hf1 = bf2f((u16)hv[1]);
        float hf2 = bf2f((u16)hv[2]), hf3 = bf2f((u16)hv[3]);
        #pragma unroll
        for (int s = 0; s < 8; s++){
          float wf = wl[t2][(hh4*8 + s) ^ (t2 & 31)];
          agg[s][0] += wf*hf0; agg[s][1] += wf*hf1;
          agg[s][2] += wf*hf2; agg[s][3] += wf*hf3;
        }
      }
    }
    __syncthreads();
  }

  // special-source aggregation
  if (tid < 192){
    #pragma unroll
    for (int e2 = 0; e2 < 8; e2++){
      s4v hv = *(const s4v*)(h + (size_t)(sbase + e2)*H + cc*4);
      float hf0 = bf2f((u16)hv[0]), hf1 = bf2f((u16)hv[1]);
      float hf2 = bf2f((u16)hv[2]), hf3 = bf2f((u16)hv[3]);
      #pragma unroll
      for (int s = 0; s < 8; s++){
        float wf = swl[s][e2][hh4];
        agg[s][0] += wf*hf0; agg[s][1] += wf*hf1;
        agg[s][2] += wf*hf2; agg[s][3] += wf*hf3;
      }
    }
  }

  // ---- denominator reduce ----
  #pragma unroll
  for (int s = 0; s < 8; s++)
    #pragma unroll
    for (int hh = 0; hh < 4; hh++){
      float v = den[s][hh];
      #pragma unroll
      for (int o = 32; o > 0; o >>= 1) v += __shfl_xor(v, o);
      den[s][hh] = v;
    }
  if (lane == 0){
    #pragma unroll
    for (int s = 0; s < 8; s++)
      #pragma unroll
      for (int hh = 0; hh < 4; hh++) red32[wave][s*4 + hh] = den[s][hh];
  }
  __syncthreads();
  if (tid < 32){
    int s = tid >> 2, hh = tid & 3;
    float v = red32[0][tid] + red32[1][tid] + red32[2][tid] + red32[3][tid];
    #pragma unroll
    for (int e2 = 0; e2 < 8; e2++) v += swl[s][e2][hh];
    denT[s][hh] = v;
  }
  __syncthreads();

  // ---- epilogue: per special s: scale, bias+relu, residual, LN, store ----
  #pragma unroll
  for (int s = 0; s < 8; s++){
    float yv[4] = {0.f,0.f,0.f,0.f};
    float sum = 0.f, sumsq = 0.f;
    size_t xoff = (size_t)(bloc*8 + s)*H + cc*4;
    if (tid < 192){
      float dinv = 1.f / (denT[s][hh4] + 1e-16f);
      s4v bv = *(const s4v*)(bias + cc*4);
      s4v xv = *(const s4v*)(xs_c + xoff);
      #pragma unroll
      for (int c = 0; c < 4; c++){
        float a = agg[s][c] * dinv;
        float o = fmaxf(a + bf2f((u16)bv[c]), 0.f);
        float y = o + bf2f((u16)xv[c]);
        yv[c] = y; sum += y; sumsq += y*y;
      }
    }
    #pragma unroll
    for (int o = 32; o > 0; o >>= 1){ sum += __shfl_xor(sum, o); sumsq += __shfl_xor(sumsq, o); }
    if (lane == 0){ wred[wave] = sum; wred[8 + wave] = sumsq; }
    __syncthreads();
    float S = wred[0] + wred[1] + wred[2] + wred[3];
    float Q = wred[8] + wred[9] + wred[10] + wred[11];
    float mean = S * (1.f/H);
    float var = Q * (1.f/H) - mean*mean;
    float rstd = rsqrtf(fmaxf(var, 0.f) + 1e-5f);
    if (tid < 192){
      s4v gv = *(const s4v*)(gamma + cc*4);
      s4v bev = *(const s4v*)(beta + cc*4);
      s4v wv;
      #pragma unroll
      for (int c = 0; c < 4; c++){
        float o = (yv[c] - mean) * rstd * bf2f((u16)gv[c]) + bf2f((u16)bev[c]);
        wv[c] = (short)f2bf(o);
      }
      *(s4v*)(xs_c + xoff) = wv;
    }
    __syncthreads();
  }
}

extern "C" void kernel_launch(void* const* d_in, const int* in_sizes, int n_in,
                              void* d_out, int out_size, void* d_ws, size_t ws_size,
                              hipStream_t stream){
  const void* text  = d_in[0];
  const void* label = d_in[1];
  const void* image = d_in[2];

  auto align256 = [](size_t x){ return (x + 255) & ~(size_t)255; };
  auto baseNeed = [&](int cand) -> size_t {
    int ct = MTEXT/cand, cs = MSPEC/cand;
    int st = (cs + 127)/128;
    size_t hr = (size_t)ct + (size_t)st*128;
    return align256(4)
         + align256(hr*H*2)
         + align256((size_t)(MSPEC+64)*H*2)
         + 2*align256((size_t)MTEXT*4)
         + align256((size_t)MSPEC*4)
         + 2*align256(hr*4*4)
         + align256((size_t)3*H*H*2)
         + 5*align256((size_t)3*H*2);
  };
  size_t bfExtra = 2*align256((size_t)MTEXT*H*2);   // xt_bf + xint

  // deterministic config from ws_size (graph-safe)
  int useBf = 0, nch = 8;
  for (int cand = 1; cand <= 8; cand <<= 1){
    if (baseNeed(cand) + bfExtra <= ws_size){ useBf = 1; nch = cand; break; }
  }
  if (!useBf){
    for (int cand = 1; cand <= 8; cand <<= 1){
      if (baseNeed(cand) <= ws_size || cand == 8){ nch = cand; break; }
    }
  }
  int ctext = MTEXT/nch, cspec = MSPEC/nch;
  int spec_tiles = (cspec + 127)/128;
  int hrows = ctext + spec_tiles*128;
  int text_tiles = ctext / 128;

  char* ws = (char*)d_ws;
  size_t off = 0;
  auto alloc = [&](size_t bytes) -> void* {
    void* p = ws + off; off += (bytes + 255) & ~(size_t)255; return p;
  };
  int*   flag = (int*)  alloc(4);
  u16*   h    = (u16*)  alloc((size_t)hrows*H*2);
  u16*   xs   = (u16*)  alloc((size_t)(MSPEC+64)*H*2);
  int*   exl  = (int*)  alloc((size_t)MTEXT*4);
  int*   exi  = (int*)  alloc((size_t)MTEXT*4);
  float* nrm  = (float*)alloc((size_t)MSPEC*4);
  float* es   = (float*)alloc((size_t)hrows*4*4);
  float* ed   = (float*)alloc((size_t)hrows*4*4);
  u16*   Wc   = (u16*)  alloc((size_t)3*H*H*2);
  u16*   asc  = (u16*)  alloc((size_t)3*H*2);
  u16*   adc  = (u16*)  alloc((size_t)3*H*2);
  u16*   bc   = (u16*)  alloc((size_t)3*H*2);
  u16*   gc   = (u16*)  alloc((size_t)3*H*2);
  u16*   bec  = (u16*)  alloc((size_t)3*H*2);
  u16*   xt_bf = nullptr;
  u16*   xint  = nullptr;
  if (useBf){
    xt_bf = (u16*)alloc((size_t)MTEXT*H*2);
    xint  = (u16*)alloc((size_t)MTEXT*H*2);
  }

  detect_kernel<<<1, 256, 0, stream>>>((const u16*)text, flag);
  convert_kernel<<<(3*H*H + 255)/256, 256, 0, stream>>>(d_in[3], Wc, 3*H*H, flag);
  convert_kernel<<<9, 256, 0, stream>>>(d_in[4], asc, 3*H, flag);
  convert_kernel<<<9, 256, 0, stream>>>(d_in[5], adc, 3*H, flag);
  convert_kernel<<<9, 256, 0, stream>>>(d_in[6], bc,  3*H, flag);
  convert_kernel<<<9, 256, 0, stream>>>(d_in[7], gc,  3*H, flag);
  convert_kernel<<<9, 256, 0, stream>>>(d_in[8], bec, 3*H, flag);

  prep_spec_kernel<<<MSPEC, 256, 0, stream>>>(label, image, xs, nrm, flag);
  topk_kernel<<<dim3(T, B), 64, 0, stream>>>(text, label, image, nrm, exl, exi, flag);
  if (useBf)
    convert_text_kernel<<<(MTEXT*H/4 + 255)/256, 256, 0, stream>>>(text, xt_bf, flag);

  for (int l = 0; l < 3; l++){
    const void* At; int forceBf;
    if (useBf){ At = (l == 0) ? (const void*)xt_bf : (const void*)xint; forceBf = 1; }
    else      { At = (l == 0) ? text : (const void*)d_out;              forceBf = 0; }
    const u16* xres = useBf ? ((l == 0) ? xt_bf : xint) : nullptr;
    const void* xraw = (l == 0) ? text : (const void*)d_out;
    int outRaw = (!useBf) || (l == 2);

    for (int c = 0; c < nch; c++){
      gemm_kernel<<<(text_tiles + spec_tiles)*6, 256, 0, stream>>>(
          At, c*ctext, xs + (size_t)c*cspec*H, Wc + (size_t)l*H*H, h,
          text_tiles, ctext, forceBf, flag);
      node_att_kernel<<<ctext + cspec, 256, 0, stream>>>(
          h, asc + l*H, adc + l*H, es, ed);
      attn_spec_kernel<<<cspec/8, 256, 0, stream>>>(
          h, xs + (size_t)c*cspec*H, es, ed,
          exl + c*ctext, exi + c*ctext,
          bc + l*H, gc + l*H, bec + l*H, ctext);
      attn_text_kernel<<<ctext/4, 256, 0, stream>>>(
          h, xres, xraw, c*ctext, d_out, xint,
          es, ed, exl + c*ctext, exi + c*ctext,
          bc + l*H, gc + l*H, bec + l*H,
          ctext, useBf, outRaw, flag);
    }
  }
}

// Round 6
// 821.247 us; speedup vs baseline: 1.6150x; 1.0853x over previous
//
#include <hip/hip_runtime.h>
#include <math.h>

#define B 64
#define T 512
#define H 768
#define DOUT 192
#define MTEXT (B*T)        // 32768
#define MSPEC (B*8)        // 512

typedef unsigned short u16;
typedef __attribute__((ext_vector_type(8))) short short8;
typedef __attribute__((ext_vector_type(4))) short s4v;
typedef __attribute__((ext_vector_type(4))) float floatx4;

__device__ __forceinline__ float bf2f(u16 u){
  union { float f; unsigned int i; } v; v.i = ((unsigned int)u) << 16; return v.f;
}
__device__ __forceinline__ u16 f2bf(float f){
  unsigned int u = __float_as_uint(f);
  unsigned int lsb = (u >> 16) & 1u;
  u += 0x7fffu + lsb;
  return (u16)(u >> 16);
}
__device__ __forceinline__ float lrelu(float v){ return v > 0.f ? v : 0.2f*v; }
__device__ __forceinline__ float ldv(const void* p, size_t i, int isF32){
  return isF32 ? ((const float*)p)[i] : bf2f(((const u16*)p)[i]);
}

// ---------------- detect input dtype ----------------
__global__ __launch_bounds__(256) void detect_kernel(const u16* __restrict__ raw, int* __restrict__ flag){
  __shared__ int red[256];
  int tid = threadIdx.x;
  int cnt = 0;
  for (int i = tid; i < 2048; i += 256){
    u16 u = raw[(size_t)i*2];
    int e = (u >> 7) & 0xFF;
    if (e >= 110 && e <= 135) cnt++;
  }
  red[tid] = cnt; __syncthreads();
  for (int s = 128; s > 0; s >>= 1){ if (tid < s) red[tid] += red[tid+s]; __syncthreads(); }
  if (tid == 0) *flag = (red[0] < 1024) ? 1 : 0;   // 1 => float32 inputs
}

// ---------------- convert raw param (f32 or bf16) -> bf16 ----------------
__global__ __launch_bounds__(256) void convert_kernel(const void* __restrict__ src,
                                                      u16* __restrict__ dst, int n,
                                                      const int* __restrict__ flagp){
  int i = blockIdx.x*256 + threadIdx.x;
  if (i >= n) return;
  if (*flagp) dst[i] = f2bf(((const float*)src)[i]);
  else        dst[i] = ((const u16*)src)[i];
}

// ---------------- convert text -> bf16 (vectorized, 4 elems/thread) ----------------
__global__ __launch_bounds__(256) void convert_text_kernel(const void* __restrict__ src,
                                                           u16* __restrict__ dst,
                                                           const int* __restrict__ flagp){
  size_t i = (size_t)blockIdx.x*256 + threadIdx.x;   // one group of 4 elems
  if (*flagp){
    float4 v = ((const float4*)src)[i];
    s4v o;
    o[0] = (short)f2bf(v.x); o[1] = (short)f2bf(v.y);
    o[2] = (short)f2bf(v.z); o[3] = (short)f2bf(v.w);
    ((s4v*)dst)[i] = o;
  } else {
    ((s4v*)dst)[i] = ((const s4v*)src)[i];
  }
}

// ---------------- prep specials: label/image -> xs (bf16) + sq-norms ----------------
__global__ __launch_bounds__(256) void prep_spec_kernel(const void* __restrict__ label,
                                                        const void* __restrict__ image,
                                                        u16* __restrict__ xs,
                                                        float* __restrict__ norms2,
                                                        const int* __restrict__ flagp){
  __shared__ float red[256];
  int isF32 = *flagp;
  int rr = blockIdx.x;          // 0..511
  int tid = threadIdx.x;
  int b = rr >> 3, s = rr & 7;
  const void* srcb = (s < 4) ? label : image;
  size_t base = (size_t)(b*4 + (s & 3))*H;
  float sq = 0.f;
  #pragma unroll
  for (int r = 0; r < 3; r++){
    int dd = tid + r*256;
    float f = ldv(srcb, base + dd, isF32);
    xs[(size_t)rr*H + dd] = f2bf(f);
    sq += f*f;
  }
  red[tid] = sq; __syncthreads();
  for (int ss = 128; ss > 0; ss >>= 1){ if (tid < ss) red[tid] += red[tid+ss]; __syncthreads(); }
  if (tid == 0) norms2[rr] = red[0];
}

// ---------------- topk: excluded (argmin) label/image index per (b,t) ----------------
__global__ __launch_bounds__(64) void topk_kernel(const void* __restrict__ text,
                                                  const void* __restrict__ label,
                                                  const void* __restrict__ image,
                                                  const float* __restrict__ norms2,
                                                  int* __restrict__ excl_l,
                                                  int* __restrict__ excl_i,
                                                  const int* __restrict__ flagp){
  int isF32 = *flagp;
  int t = blockIdx.x, b = blockIdx.y;
  int lane = threadIdx.x;
  float dl[4] = {0,0,0,0}, di[4] = {0,0,0,0};
  size_t tbase = (size_t)(b*T + t)*H;
  for (int r = 0; r < 12; r++){
    int d = lane + r*64;
    float tx = ldv(text, tbase + d, isF32);
    #pragma unroll
    for (int j = 0; j < 4; j++){
      dl[j] += tx * ldv(label, (size_t)(b*4 + j)*H + d, isF32);
      di[j] += tx * ldv(image, (size_t)(b*4 + j)*H + d, isF32);
    }
  }
  #pragma unroll
  for (int j = 0; j < 4; j++){
    for (int o = 32; o > 0; o >>= 1){
      dl[j] += __shfl_down(dl[j], o);
      di[j] += __shfl_down(di[j], o);
    }
  }
  if (lane == 0){
    float vl[4], vi[4];
    #pragma unroll
    for (int j = 0; j < 4; j++){
      vl[j] = dl[j] / fmaxf(sqrtf(norms2[b*8 + j]), 1e-8f);
      vi[j] = di[j] / fmaxf(sqrtf(norms2[b*8 + 4 + j]), 1e-8f);
    }
    int el = 0, ei = 0;
    #pragma unroll
    for (int j = 1; j < 4; j++){
      if (vl[j] <= vl[el]) el = j;
      if (vi[j] <= vi[ei]) ei = j;
    }
    excl_l[b*T + t] = el;
    excl_i[b*T + t] = ei;
  }
}

// ---------------- GEMM: h[hrows,768](bf16) = x @ W^T ----------------
__global__ __launch_bounds__(256) void gemm_kernel(const void* __restrict__ At, int arow0,
                                                   const u16* __restrict__ As,
                                                   const u16* __restrict__ Bw,
                                                   u16* __restrict__ C,
                                                   int text_tiles, int ctext,
                                                   int forceBf,
                                                   const int* __restrict__ flagp){
  __shared__ __align__(16) u16 lA[128*72];
  __shared__ __align__(16) u16 lB[128*72];
  int isF32 = forceBf ? 0 : *flagp;
  int tid = threadIdx.x;

  // 1-D grid, XCD-aware bijective swizzle so the 6 col-tiles sharing an
  // A-panel (consecutive logical ids) land on the same XCD's L2.
  int nb = gridDim.x;
  int bid = blockIdx.x;
  int q = nb >> 3, r = nb & 7;
  int xcd = bid & 7, ixx = bid >> 3;
  int lid = (xcd < r ? xcd*(q+1) : r*(q+1) + (xcd - r)*q) + ixx;
  int tile = lid / 6;
  int nbase = (lid % 6) * 128;

  bool spec = (tile >= text_tiles);
  int lrow0 = spec ? (tile - text_tiles)*128 : tile*128;
  int crow0 = spec ? (ctext + lrow0) : lrow0;
  const u16*   Abf = spec ? (As + (size_t)lrow0*H)
                          : ((const u16*)At + (size_t)(arow0 + lrow0)*H);
  const float* Af  = (const float*)At + (size_t)(arow0 + lrow0)*H;
  int wave = tid >> 6, lane = tid & 63;
  int wm = (wave >> 1) * 64, wn = (wave & 1) * 64;
  int lrow = lane & 15, lkq = (lane >> 4) * 8;
  int r0 = tid >> 3;
  int c0 = (tid & 7) * 8;

  floatx4 acc[4][4];
  #pragma unroll
  for (int i = 0; i < 4; i++)
    #pragma unroll
    for (int j = 0; j < 4; j++)
      acc[i][j] = (floatx4){0.f,0.f,0.f,0.f};

  for (int k0 = 0; k0 < H; k0 += 64){
    short8 va[4], vb[4];
    #pragma unroll
    for (int i = 0; i < 4; i++){
      int row = i*32 + r0;
      if (spec || !isF32) va[i] = *(const short8*)(Abf + (size_t)row*H + k0 + c0);
      else {
        const float* p = Af + (size_t)row*H + k0 + c0;
        float4 lo = *(const float4*)p;
        float4 hi = *(const float4*)(p + 4);
        short8 tv;
        tv[0]=(short)f2bf(lo.x); tv[1]=(short)f2bf(lo.y); tv[2]=(short)f2bf(lo.z); tv[3]=(short)f2bf(lo.w);
        tv[4]=(short)f2bf(hi.x); tv[5]=(short)f2bf(hi.y); tv[6]=(short)f2bf(hi.z); tv[7]=(short)f2bf(hi.w);
        va[i] = tv;
      }
      vb[i] = *(const short8*)(Bw + (size_t)(nbase + row)*H + k0 + c0);
    }
    __syncthreads();
    #pragma unroll
    for (int i = 0; i < 4; i++){
      int row = i*32 + r0;
      *(short8*)(lA + row*72 + c0) = va[i];
      *(short8*)(lB + row*72 + c0) = vb[i];
    }
    __syncthreads();
    #pragma unroll
    for (int kk = 0; kk < 2; kk++){
      short8 af[4], bfv[4];
      #pragma unroll
      for (int i = 0; i < 4; i++){
        af[i]  = *(const short8*)(lA + (wm + i*16 + lrow)*72 + kk*32 + lkq);
        bfv[i] = *(const short8*)(lB + (wn + i*16 + lrow)*72 + kk*32 + lkq);
      }
      #pragma unroll
      for (int i = 0; i < 4; i++)
        #pragma unroll
        for (int j = 0; j < 4; j++)
          acc[i][j] = __builtin_amdgcn_mfma_f32_16x16x32_bf16(af[i], bfv[j], acc[i][j], 0, 0, 0);
    }
  }
  int qrow = (lane >> 4) * 4;
  int col = lane & 15;
  #pragma unroll
  for (int i = 0; i < 4; i++)
    #pragma unroll
    for (int j = 0; j < 4; j++)
      #pragma unroll
      for (int r2 = 0; r2 < 4; r2++){
        int grow = crow0 + wm + i*16 + qrow + r2;
        int gcol = nbase + wn + j*16 + col;
        C[(size_t)grow*H + gcol] = f2bf(acc[i][j][r2]);
      }
}

// ---------------- per-node es/ed: block per node, vectorized short4 loads ----------------
__global__ __launch_bounds__(256) void node_att_kernel(const u16* __restrict__ h,
                                                       const u16* __restrict__ a_s,
                                                       const u16* __restrict__ a_d,
                                                       float* __restrict__ es,
                                                       float* __restrict__ ed){
  int node = blockIdx.x;
  int head = threadIdx.x >> 6, lane = threadIdx.x & 63;
  float s = 0.f, d = 0.f;
  if (lane < 48){
    s4v hv = *(const s4v*)(h   + (size_t)node*H + head*DOUT + lane*4);
    s4v sv = *(const s4v*)(a_s + head*DOUT + lane*4);
    s4v dv = *(const s4v*)(a_d + head*DOUT + lane*4);
    #pragma unroll
    for (int c = 0; c < 4; c++){
      float hf = bf2f((u16)hv[c]);
      s += hf * bf2f((u16)sv[c]);
      d += hf * bf2f((u16)dv[c]);
    }
  }
  #pragma unroll
  for (int o = 32; o > 0; o >>= 1){ s += __shfl_down(s, o); d += __shfl_down(d, o); }
  if (lane == 0){ es[node*4 + head] = s; ed[node*4 + head] = d; }
}

// ---------------- attention, text destinations (wave-per-node, XCD swizzle) ----------------
__global__ __launch_bounds__(256) void attn_text_kernel(
    const u16* __restrict__ h,
    const u16* __restrict__ xres,        // bf16 residual source (when resBf)
    const void* __restrict__ xraw,       // raw residual source (when !resBf)
    int xrow0,
    void* __restrict__ xout,             // d_out (when outRaw)
    u16* __restrict__ xoutbf,            // xint (when !outRaw)
    const float* __restrict__ es, const float* __restrict__ ed,
    const int* __restrict__ exl_c, const int* __restrict__ exi_c,
    const u16* __restrict__ bias, const u16* __restrict__ gamma, const u16* __restrict__ beta,
    int ctext, int resBf, int outRaw, const int* __restrict__ flagp){
  __shared__ float alpha_l[4][9][4];

  int isF32 = *flagp;
  int tid = threadIdx.x, wave = tid >> 6, lane = tid & 63;

  // XCD-aware bijective swizzle (contiguous logical chunk per XCD)
  int nb = gridDim.x;
  int bid = blockIdx.x;
  int q = nb >> 3, r = nb & 7;
  int xcd = bid & 7, ixx = bid >> 3;
  int lb = (xcd < r ? xcd*(q+1) : r*(q+1) + (xcd - r)*q) + ixx;

  int loc = lb*4 + wave;
  int bloc = loc >> 9, t = loc & 511;
  int el = exl_c[loc], ei = exi_c[loc];
  int sbase = ctext + bloc*8;

  // wave-parallel softmax: lane = e*4 + hh (36 active lanes)
  int e = lane >> 2, hh = lane & 3;
  bool act = (e < 9) && !(e == 1 && t == 0) && !(e == 2 && t == T-1);
  int srcE;
  if (e == 0)      srcE = loc;
  else if (e == 1) srcE = loc - 1;
  else if (e == 2) srcE = loc + 1;
  else if (e < 6){ int k = e - 3; srcE = sbase + k + (k >= el ? 1 : 0); }
  else           { int k = e - 6; srcE = sbase + 4 + (k & 3) + ((k & 3) >= ei ? 1 : 0); }
  float v = -1e30f;
  if (act) v = lrelu(es[srcE*4 + hh] + ed[loc*4 + hh]);
  float m = v;
  #pragma unroll
  for (int o = 4; o < 64; o <<= 1) m = fmaxf(m, __shfl_xor(m, o));
  float w = act ? expf(fminf(v - m, 0.f)) : 0.f;
  float den = w;
  #pragma unroll
  for (int o = 4; o < 64; o <<= 1) den += __shfl_xor(den, o);
  if (e < 9) alpha_l[wave][e][hh] = w / (den + 1e-16f);
  __syncthreads();

  // source ids (compile-time indexed only)
  int srcs[9];
  srcs[0] = loc;
  srcs[1] = (t > 0)   ? loc - 1 : loc;
  srcs[2] = (t < T-1) ? loc + 1 : loc;
  #pragma unroll
  for (int k = 0; k < 3; k++){
    srcs[3+k] = sbase + k + (k >= el ? 1 : 0);
    srcs[6+k] = sbase + 4 + k + (k >= ei ? 1 : 0);
  }

  // aggregation: lane owns 3 chunks of 4 contiguous dims
  int d0 = lane*4;
  int hk0 = d0/DOUT, hk1 = (d0+256)/DOUT, hk2 = (d0+512)/DOUT;
  float a0[4] = {0,0,0,0}, a1[4] = {0,0,0,0}, a2[4] = {0,0,0,0};
  #pragma unroll
  for (int ee = 0; ee < 9; ee++){
    const u16* hp = h + (size_t)srcs[ee]*H + d0;
    s4v v0 = *(const s4v*)(hp);
    s4v v1 = *(const s4v*)(hp + 256);
    s4v v2 = *(const s4v*)(hp + 512);
    float al0 = alpha_l[wave][ee][hk0];
    float al1 = alpha_l[wave][ee][hk1];
    float al2 = alpha_l[wave][ee][hk2];
    #pragma unroll
    for (int c = 0; c < 4; c++){
      a0[c] += al0 * bf2f((u16)v0[c]);
      a1[c] += al1 * bf2f((u16)v1[c]);
      a2[c] += al2 * bf2f((u16)v2[c]);
    }
  }

  // bias + relu + residual + LN (in-wave butterfly)
  size_t xoff = (size_t)(xrow0 + loc)*H + d0;
  s4v b0 = *(const s4v*)(bias + d0);
  s4v b1 = *(const s4v*)(bias + d0 + 256);
  s4v b2 = *(const s4v*)(bias + d0 + 512);
  float xr0[4], xr1[4], xr2[4];
  if (resBf){
    const u16* xp = xres + xoff;
    s4v x0 = *(const s4v*)xp;
    s4v x1 = *(const s4v*)(xp + 256);
    s4v x2 = *(const s4v*)(xp + 512);
    #pragma unroll
    for (int c = 0; c < 4; c++){
      xr0[c] = bf2f((u16)x0[c]); xr1[c] = bf2f((u16)x1[c]); xr2[c] = bf2f((u16)x2[c]);
    }
  } else if (isF32){
    const float* xp = (const float*)xraw + xoff;
    float4 x0 = *(const float4*)xp;
    float4 x1 = *(const float4*)(xp + 256);
    float4 x2 = *(const float4*)(xp + 512);
    xr0[0]=x0.x; xr0[1]=x0.y; xr0[2]=x0.z; xr0[3]=x0.w;
    xr1[0]=x1.x; xr1[1]=x1.y; xr1[2]=x1.z; xr1[3]=x1.w;
    xr2[0]=x2.x; xr2[1]=x2.y; xr2[2]=x2.z; xr2[3]=x2.w;
  } else {
    const u16* xp = (const u16*)xraw + xoff;
    s4v x0 = *(const s4v*)xp;
    s4v x1 = *(const s4v*)(xp + 256);
    s4v x2 = *(const s4v*)(xp + 512);
    #pragma unroll
    for (int c = 0; c < 4; c++){
      xr0[c] = bf2f((u16)x0[c]); xr1[c] = bf2f((u16)x1[c]); xr2[c] = bf2f((u16)x2[c]);
    }
  }
  float y0[4], y1[4], y2[4];
  float sum = 0.f, sumsq = 0.f;
  #pragma unroll
  for (int c = 0; c < 4; c++){
    y0[c] = fmaxf(a0[c] + bf2f((u16)b0[c]), 0.f) + xr0[c];
    y1[c] = fmaxf(a1[c] + bf2f((u16)b1[c]), 0.f) + xr1[c];
    y2[c] = fmaxf(a2[c] + bf2f((u16)b2[c]), 0.f) + xr2[c];
    sum   += y0[c] + y1[c] + y2[c];
    sumsq += y0[c]*y0[c] + y1[c]*y1[c] + y2[c]*y2[c];
  }
  #pragma unroll
  for (int o = 1; o < 64; o <<= 1){
    sum   += __shfl_xor(sum, o);
    sumsq += __shfl_xor(sumsq, o);
  }
  float mean = sum * (1.f/H);
  float var = sumsq * (1.f/H) - mean*mean;
  float rstd = rsqrtf(fmaxf(var, 0.f) + 1e-5f);
  s4v g0 = *(const s4v*)(gamma + d0);
  s4v g1 = *(const s4v*)(gamma + d0 + 256);
  s4v g2 = *(const s4v*)(gamma + d0 + 512);
  s4v be0 = *(const s4v*)(beta + d0);
  s4v be1 = *(const s4v*)(beta + d0 + 256);
  s4v be2 = *(const s4v*)(beta + d0 + 512);
  float o0[4], o1[4], o2[4];
  #pragma unroll
  for (int c = 0; c < 4; c++){
    o0[c] = (y0[c] - mean) * rstd * bf2f((u16)g0[c]) + bf2f((u16)be0[c]);
    o1[c] = (y1[c] - mean) * rstd * bf2f((u16)g1[c]) + bf2f((u16)be1[c]);
    o2[c] = (y2[c] - mean) * rstd * bf2f((u16)g2[c]) + bf2f((u16)be2[c]);
  }
  if (!outRaw){
    u16* xo = xoutbf + xoff;
    s4v w0, w1, w2;
    #pragma unroll
    for (int c = 0; c < 4; c++){
      w0[c] = (short)f2bf(o0[c]); w1[c] = (short)f2bf(o1[c]); w2[c] = (short)f2bf(o2[c]);
    }
    *(s4v*)xo = w0; *(s4v*)(xo + 256) = w1; *(s4v*)(xo + 512) = w2;
  } else if (isF32){
    float* xo = (float*)xout + xoff;
    float4 w0, w1, w2;
    w0.x=o0[0]; w0.y=o0[1]; w0.z=o0[2]; w0.w=o0[3];
    w1.x=o1[0]; w1.y=o1[1]; w1.z=o1[2]; w1.w=o1[3];
    w2.x=o2[0]; w2.y=o2[1]; w2.z=o2[2]; w2.w=o2[3];
    *(float4*)xo = w0; *(float4*)(xo + 256) = w1; *(float4*)(xo + 512) = w2;
  } else {
    u16* xo = (u16*)xout + xoff;
    s4v w0, w1, w2;
    #pragma unroll
    for (int c = 0; c < 4; c++){
      w0[c] = (short)f2bf(o0[c]); w1[c] = (short)f2bf(o1[c]); w2[c] = (short)f2bf(o2[c]);
    }
    *(s4v*)xo = w0; *(s4v*)(xo + 256) = w1; *(s4v*)(xo + 512) = w2;
  }
}

// ---------------- attention, special destinations: one block per (batch,special) ----------------
// (round-2 harness-proven body, no swizzle)
__global__ __launch_bounds__(256) void attn_spec_kernel(
    const u16* __restrict__ h, u16* __restrict__ xs_c,
    const float* __restrict__ es, const float* __restrict__ ed,
    const int* __restrict__ exl_c, const int* __restrict__ exi_c,
    const u16* __restrict__ bias, const u16* __restrict__ gamma, const u16* __restrict__ beta,
    int ctext){
  __shared__ float wred[16];
  __shared__ float wdyn[512][4];
  __shared__ float sw[8][4];
  __shared__ float wm4[4][4], wsum4[4][4];

  int tid = threadIdx.x, wave = tid >> 6, lane = tid & 63;

  int idx = blockIdx.x;
  int bloc = idx >> 3, s = idx & 7;
  int node = ctext + idx;
  const int* excl = (s < 4) ? exl_c : exi_c;
  int target = s & 3;
  float edv[4];
  #pragma unroll
  for (int hh = 0; hh < 4; hh++) edv[hh] = ed[node*4 + hh];

  int t0 = tid, t1 = tid + 256;
  bool sel0 = (excl[bloc*512 + t0] != target);
  bool sel1 = (excl[bloc*512 + t1] != target);
  const float* e0 = es + (size_t)(bloc*512 + t0)*4;
  const float* e1 = es + (size_t)(bloc*512 + t1)*4;
  float v0[4], v1[4], vs[4], m[4];
  #pragma unroll
  for (int hh = 0; hh < 4; hh++){
    v0[hh] = sel0 ? lrelu(e0[hh] + edv[hh]) : -1e30f;
    v1[hh] = sel1 ? lrelu(e1[hh] + edv[hh]) : -1e30f;
    m[hh] = fmaxf(v0[hh], v1[hh]);
  }
  if (tid < 8){
    const float* ep = es + (size_t)(ctext + bloc*8 + tid)*4;
    #pragma unroll
    for (int hh = 0; hh < 4; hh++){ vs[hh] = lrelu(ep[hh] + edv[hh]); m[hh] = fmaxf(m[hh], vs[hh]); }
  }
  #pragma unroll
  for (int hh = 0; hh < 4; hh++)
    for (int o = 32; o > 0; o >>= 1) m[hh] = fmaxf(m[hh], __shfl_down(m[hh], o));
  if (lane == 0){
    #pragma unroll
    for (int hh = 0; hh < 4; hh++) wm4[wave][hh] = m[hh];
  }
  __syncthreads();
  #pragma unroll
  for (int hh = 0; hh < 4; hh++)
    m[hh] = fmaxf(fmaxf(wm4[0][hh], wm4[1][hh]), fmaxf(wm4[2][hh], wm4[3][hh]));

  float ds[4];
  #pragma unroll
  for (int hh = 0; hh < 4; hh++){
    float w0 = sel0 ? expf(fminf(v0[hh] - m[hh], 0.f)) : 0.f;
    float w1 = sel1 ? expf(fminf(v1[hh] - m[hh], 0.f)) : 0.f;
    wdyn[t0][hh] = w0; wdyn[t1][hh] = w1;
    ds[hh] = w0 + w1;
  }
  if (tid < 8){
    #pragma unroll
    for (int hh = 0; hh < 4; hh++){
      float w = expf(fminf(vs[hh] - m[hh], 0.f));
      sw[tid][hh] = w; ds[hh] += w;
    }
  }
  #pragma unroll
  for (int hh = 0; hh < 4; hh++)
    for (int o = 32; o > 0; o >>= 1) ds[hh] += __shfl_down(ds[hh], o);
  if (lane == 0){
    #pragma unroll
    for (int hh = 0; hh < 4; hh++) wsum4[wave][hh] = ds[hh];
  }
  __syncthreads();   // also makes wdyn/sw visible

  // aggregation: thread cc<192 owns 4 contiguous dims, vectorized short4 loads
  int cc = tid;
  int hh4 = (cc < 192) ? (cc/48) : 0;
  float dinv = 1.f / (wsum4[0][hh4] + wsum4[1][hh4] + wsum4[2][hh4] + wsum4[3][hh4] + 1e-16f);
  float agg[4] = {0.f, 0.f, 0.f, 0.f};
  if (cc < 192){
    const u16* hp = h + (size_t)(bloc*512)*H + cc*4;
    #pragma unroll 8
    for (int tt = 0; tt < 512; tt++){
      s4v hv = *(const s4v*)(hp + (size_t)tt*H);
      float wv = wdyn[tt][hh4];
      agg[0] += wv * bf2f((u16)hv[0]);
      agg[1] += wv * bf2f((u16)hv[1]);
      agg[2] += wv * bf2f((u16)hv[2]);
      agg[3] += wv * bf2f((u16)hv[3]);
    }
    #pragma unroll
    for (int e2 = 0; e2 < 8; e2++){
      s4v hv = *(const s4v*)(h + (size_t)(ctext + bloc*8 + e2)*H + cc*4);
      float wv = sw[e2][hh4];
      agg[0] += wv * bf2f((u16)hv[0]);
      agg[1] += wv * bf2f((u16)hv[1]);
      agg[2] += wv * bf2f((u16)hv[2]);
      agg[3] += wv * bf2f((u16)hv[3]);
    }
  }
  float y[4] = {0.f,0.f,0.f,0.f};
  float sum = 0.f, sumsq = 0.f;
  if (cc < 192){
    s4v bv = *(const s4v*)(bias + cc*4);
    s4v xv = *(const s4v*)(xs_c + (size_t)idx*H + cc*4);
    #pragma unroll
    for (int c = 0; c < 4; c++){
      float a = agg[c] * dinv;
      float o = fmaxf(a + bf2f((u16)bv[c]), 0.f);
      float yv = o + bf2f((u16)xv[c]);
      y[c] = yv; sum += yv; sumsq += yv*yv;
    }
  }
  for (int o = 32; o > 0; o >>= 1){ sum += __shfl_down(sum, o); sumsq += __shfl_down(sumsq, o); }
  if (lane == 0){ wred[wave] = sum; wred[8 + wave] = sumsq; }
  __syncthreads();
  sum   = wred[0] + wred[1] + wred[2] + wred[3];
  sumsq = wred[8] + wred[9] + wred[10] + wred[11];
  float mean = sum * (1.f/H);
  float var = sumsq * (1.f/H) - mean*mean;
  float rstd = rsqrtf(fmaxf(var, 0.f) + 1e-5f);
  if (cc < 192){
    s4v gv = *(const s4v*)(gamma + cc*4);
    s4v bev = *(const s4v*)(beta + cc*4);
    s4v wv;
    #pragma unroll
    for (int c = 0; c < 4; c++){
      float o = (y[c] - mean) * rstd * bf2f((u16)gv[c]) + bf2f((u16)bev[c]);
      wv[c] = (short)f2bf(o);
    }
    *(s4v*)(xs_c + (size_t)idx*H + cc*4) = wv;
  }
}

extern "C" void kernel_launch(void* const* d_in, const int* in_sizes, int n_in,
                              void* d_out, int out_size, void* d_ws, size_t ws_size,
                              hipStream_t stream){
  const void* text  = d_in[0];
  const void* label = d_in[1];
  const void* image = d_in[2];

  auto align256 = [](size_t x){ return (x + 255) & ~(size_t)255; };
  auto baseNeed = [&](int cand) -> size_t {
    int ct = MTEXT/cand, cs = MSPEC/cand;
    int st = (cs + 127)/128;
    size_t hr = (size_t)ct + (size_t)st*128;
    return align256(4)
         + align256(hr*H*2)
         + align256((size_t)(MSPEC+64)*H*2)
         + 2*align256((size_t)MTEXT*4)
         + align256((size_t)MSPEC*4)
         + 2*align256(hr*4*4)
         + align256((size_t)3*H*H*2)
         + 5*align256((size_t)3*H*2);
  };
  size_t bfExtra = 2*align256((size_t)MTEXT*H*2);   // xt_bf + xint

  // deterministic config from ws_size (graph-safe)
  int useBf = 0, nch = 8;
  for (int cand = 1; cand <= 8; cand <<= 1){
    if (baseNeed(cand) + bfExtra <= ws_size){ useBf = 1; nch = cand; break; }
  }
  if (!useBf){
    for (int cand = 1; cand <= 8; cand <<= 1){
      if (baseNeed(cand) <= ws_size || cand == 8){ nch = cand; break; }
    }
  }
  int ctext = MTEXT/nch, cspec = MSPEC/nch;
  int spec_tiles = (cspec + 127)/128;
  int hrows = ctext + spec_tiles*128;
  int text_tiles = ctext / 128;

  char* ws = (char*)d_ws;
  size_t off = 0;
  auto alloc = [&](size_t bytes) -> void* {
    void* p = ws + off; off += (bytes + 255) & ~(size_t)255; return p;
  };
  int*   flag = (int*)  alloc(4);
  u16*   h    = (u16*)  alloc((size_t)hrows*H*2);
  u16*   xs   = (u16*)  alloc((size_t)(MSPEC+64)*H*2);
  int*   exl  = (int*)  alloc((size_t)MTEXT*4);
  int*   exi  = (int*)  alloc((size_t)MTEXT*4);
  float* nrm  = (float*)alloc((size_t)MSPEC*4);
  float* es   = (float*)alloc((size_t)hrows*4*4);
  float* ed   = (float*)alloc((size_t)hrows*4*4);
  u16*   Wc   = (u16*)  alloc((size_t)3*H*H*2);
  u16*   asc  = (u16*)  alloc((size_t)3*H*2);
  u16*   adc  = (u16*)  alloc((size_t)3*H*2);
  u16*   bc   = (u16*)  alloc((size_t)3*H*2);
  u16*   gc   = (u16*)  alloc((size_t)3*H*2);
  u16*   bec  = (u16*)  alloc((size_t)3*H*2);
  u16*   xt_bf = nullptr;
  u16*   xint  = nullptr;
  if (useBf){
    xt_bf = (u16*)alloc((size_t)MTEXT*H*2);
    xint  = (u16*)alloc((size_t)MTEXT*H*2);
  }

  detect_kernel<<<1, 256, 0, stream>>>((const u16*)text, flag);
  convert_kernel<<<(3*H*H + 255)/256, 256, 0, stream>>>(d_in[3], Wc, 3*H*H, flag);
  convert_kernel<<<9, 256, 0, stream>>>(d_in[4], asc, 3*H, flag);
  convert_kernel<<<9, 256, 0, stream>>>(d_in[5], adc, 3*H, flag);
  convert_kernel<<<9, 256, 0, stream>>>(d_in[6], bc,  3*H, flag);
  convert_kernel<<<9, 256, 0, stream>>>(d_in[7], gc,  3*H, flag);
  convert_kernel<<<9, 256, 0, stream>>>(d_in[8], bec, 3*H, flag);

  prep_spec_kernel<<<MSPEC, 256, 0, stream>>>(label, image, xs, nrm, flag);
  topk_kernel<<<dim3(T, B), 64, 0, stream>>>(text, label, image, nrm, exl, exi, flag);
  if (useBf)
    convert_text_kernel<<<(MTEXT*H/4 + 255)/256, 256, 0, stream>>>(text, xt_bf, flag);

  for (int l = 0; l < 3; l++){
    const void* At; int forceBf;
    if (useBf){ At = (l == 0) ? (const void*)xt_bf : (const void*)xint; forceBf = 1; }
    else      { At = (l == 0) ? text : (const void*)d_out;              forceBf = 0; }
    const u16* xres = useBf ? ((l == 0) ? xt_bf : xint) : nullptr;
    const void* xraw = (l == 0) ? text : (const void*)d_out;
    int outRaw = (!useBf) || (l == 2);

    for (int c = 0; c < nch; c++){
      gemm_kernel<<<(text_tiles + spec_tiles)*6, 256, 0, stream>>>(
          At, c*ctext, xs + (size_t)c*cspec*H, Wc + (size_t)l*H*H, h,
          text_tiles, ctext, forceBf, flag);
      node_att_kernel<<<ctext + cspec, 256, 0, stream>>>(
          h, asc + l*H, adc + l*H, es, ed);
      attn_spec_kernel<<<cspec, 256, 0, stream>>>(
          h, xs + (size_t)c*cspec*H, es, ed,
          exl + c*ctext, exi + c*ctext,
          bc + l*H, gc + l*H, bec + l*H, ctext);
      attn_text_kernel<<<ctext/4, 256, 0, stream>>>(
          h, xres, xraw, c*ctext, d_out, xint,
          es, ed, exl + c*ctext, exi + c*ctext,
          bc + l*H, gc + l*H, bec + l*H,
          ctext, useBf, outRaw, flag);
    }
  }
}

// Round 7
// 762.996 us; speedup vs baseline: 1.7383x; 1.0763x over previous
//
#include <hip/hip_runtime.h>
#include <math.h>

#define B 64
#define T 512
#define H 768
#define DOUT 192
#define MTEXT (B*T)        // 32768
#define MSPEC (B*8)        // 512

typedef unsigned short u16;
typedef __attribute__((ext_vector_type(8))) short short8;
typedef __attribute__((ext_vector_type(4))) short s4v;
typedef __attribute__((ext_vector_type(4))) float floatx4;

__device__ __forceinline__ float bf2f(u16 u){
  union { float f; unsigned int i; } v; v.i = ((unsigned int)u) << 16; return v.f;
}
__device__ __forceinline__ u16 f2bf(float f){
  unsigned int u = __float_as_uint(f);
  unsigned int lsb = (u >> 16) & 1u;
  u += 0x7fffu + lsb;
  return (u16)(u >> 16);
}
__device__ __forceinline__ float lrelu(float v){ return v > 0.f ? v : 0.2f*v; }
__device__ __forceinline__ float ldv(const void* p, size_t i, int isF32){
  return isF32 ? ((const float*)p)[i] : bf2f(((const u16*)p)[i]);
}

// ---------------- detect input dtype ----------------
__global__ __launch_bounds__(256) void detect_kernel(const u16* __restrict__ raw, int* __restrict__ flag){
  __shared__ int red[256];
  int tid = threadIdx.x;
  int cnt = 0;
  for (int i = tid; i < 2048; i += 256){
    u16 u = raw[(size_t)i*2];
    int e = (u >> 7) & 0xFF;
    if (e >= 110 && e <= 135) cnt++;
  }
  red[tid] = cnt; __syncthreads();
  for (int s = 128; s > 0; s >>= 1){ if (tid < s) red[tid] += red[tid+s]; __syncthreads(); }
  if (tid == 0) *flag = (red[0] < 1024) ? 1 : 0;   // 1 => float32 inputs
}

// ---------------- convert raw param (f32 or bf16) -> bf16 ----------------
__global__ __launch_bounds__(256) void convert_kernel(const void* __restrict__ src,
                                                      u16* __restrict__ dst, int n,
                                                      const int* __restrict__ flagp){
  int i = blockIdx.x*256 + threadIdx.x;
  if (i >= n) return;
  if (*flagp) dst[i] = f2bf(((const float*)src)[i]);
  else        dst[i] = ((const u16*)src)[i];
}

// ---------------- convert text -> bf16 (vectorized, 4 elems/thread) ----------------
__global__ __launch_bounds__(256) void convert_text_kernel(const void* __restrict__ src,
                                                           u16* __restrict__ dst,
                                                           const int* __restrict__ flagp){
  size_t i = (size_t)blockIdx.x*256 + threadIdx.x;   // one group of 4 elems
  if (*flagp){
    float4 v = ((const float4*)src)[i];
    s4v o;
    o[0] = (short)f2bf(v.x); o[1] = (short)f2bf(v.y);
    o[2] = (short)f2bf(v.z); o[3] = (short)f2bf(v.w);
    ((s4v*)dst)[i] = o;
  } else {
    ((s4v*)dst)[i] = ((const s4v*)src)[i];
  }
}

// ---------------- prep specials: label/image -> xs (bf16) + sq-norms ----------------
__global__ __launch_bounds__(256) void prep_spec_kernel(const void* __restrict__ label,
                                                        const void* __restrict__ image,
                                                        u16* __restrict__ xs,
                                                        float* __restrict__ norms2,
                                                        const int* __restrict__ flagp){
  __shared__ float red[256];
  int isF32 = *flagp;
  int rr = blockIdx.x;          // 0..511
  int tid = threadIdx.x;
  int b = rr >> 3, s = rr & 7;
  const void* srcb = (s < 4) ? label : image;
  size_t base = (size_t)(b*4 + (s & 3))*H;
  float sq = 0.f;
  #pragma unroll
  for (int r = 0; r < 3; r++){
    int dd = tid + r*256;
    float f = ldv(srcb, base + dd, isF32);
    xs[(size_t)rr*H + dd] = f2bf(f);
    sq += f*f;
  }
  red[tid] = sq; __syncthreads();
  for (int ss = 128; ss > 0; ss >>= 1){ if (tid < ss) red[tid] += red[tid+ss]; __syncthreads(); }
  if (tid == 0) norms2[rr] = red[0];
}

// ---------------- topk v2: LDS-staged specials, 16 text rows per block ----------------
__global__ __launch_bounds__(256) void topk_kernel(const void* __restrict__ text,
                                                   const void* __restrict__ label,
                                                   const void* __restrict__ image,
                                                   const float* __restrict__ norms2,
                                                   int* __restrict__ excl_l,
                                                   int* __restrict__ excl_i,
                                                   const int* __restrict__ flagp){
  __shared__ float spec[8*H];            // 24 KB
  int isF32 = *flagp;
  int tid = threadIdx.x, wave = tid >> 6, lane = tid & 63;
  int b = blockIdx.y;

  // stage 8 special rows (4 label + 4 image) into LDS as f32
  if (isF32){
    const float* lb = (const float*)label + (size_t)b*4*H;
    const float* im = (const float*)image + (size_t)b*4*H;
    #pragma unroll
    for (int j = 0; j < 6; j++){
      int idx = tid + j*256;             // float4 index, 0..1535
      int flat = idx*4;
      int s = flat / H, d = flat % H;
      const float* src = (s < 4) ? (lb + (size_t)s*H + d) : (im + (size_t)(s-4)*H + d);
      *(float4*)(spec + s*H + d) = *(const float4*)src;
    }
  } else {
    const u16* lb = (const u16*)label + (size_t)b*4*H;
    const u16* im = (const u16*)image + (size_t)b*4*H;
    #pragma unroll
    for (int j = 0; j < 6; j++){
      int idx = tid + j*256;
      int flat = idx*4;
      int s = flat / H, d = flat % H;
      const u16* src = (s < 4) ? (lb + (size_t)s*H + d) : (im + (size_t)(s-4)*H + d);
      s4v v = *(const s4v*)src;
      float4 f;
      f.x = bf2f((u16)v[0]); f.y = bf2f((u16)v[1]);
      f.z = bf2f((u16)v[2]); f.w = bf2f((u16)v[3]);
      *(float4*)(spec + s*H + d) = f;
    }
  }
  __syncthreads();

  #pragma unroll
  for (int pass = 0; pass < 4; pass++){
    int t = blockIdx.x*16 + pass*4 + wave;
    size_t tb = ((size_t)b*T + t)*H;
    float tx[12];
    if (isF32){
      const float* tp = (const float*)text + tb;
      #pragma unroll
      for (int k = 0; k < 3; k++){
        float4 v = *(const float4*)(tp + lane*4 + k*256);
        tx[k*4+0]=v.x; tx[k*4+1]=v.y; tx[k*4+2]=v.z; tx[k*4+3]=v.w;
      }
    } else {
      const u16* tp = (const u16*)text + tb;
      #pragma unroll
      for (int k = 0; k < 3; k++){
        s4v v = *(const s4v*)(tp + lane*4 + k*256);
        tx[k*4+0]=bf2f((u16)v[0]); tx[k*4+1]=bf2f((u16)v[1]);
        tx[k*4+2]=bf2f((u16)v[2]); tx[k*4+3]=bf2f((u16)v[3]);
      }
    }
    float dot[8] = {0,0,0,0,0,0,0,0};
    #pragma unroll
    for (int k = 0; k < 3; k++){
      int d = lane*4 + k*256;
      #pragma unroll
      for (int s = 0; s < 8; s++){
        float4 sv = *(const float4*)(spec + s*H + d);
        dot[s] += tx[k*4+0]*sv.x + tx[k*4+1]*sv.y + tx[k*4+2]*sv.z + tx[k*4+3]*sv.w;
      }
    }
    #pragma unroll
    for (int s = 0; s < 8; s++)
      for (int o = 32; o > 0; o >>= 1) dot[s] += __shfl_down(dot[s], o);
    if (lane == 0){
      float vl[4], vi[4];
      #pragma unroll
      for (int j = 0; j < 4; j++){
        vl[j] = dot[j]   / fmaxf(sqrtf(norms2[b*8 + j]),     1e-8f);
        vi[j] = dot[4+j] / fmaxf(sqrtf(norms2[b*8 + 4 + j]), 1e-8f);
      }
      int el = 0, ei = 0;
      #pragma unroll
      for (int j = 1; j < 4; j++){
        if (vl[j] <= vl[el]) el = j;
        if (vi[j] <= vi[ei]) ei = j;
      }
      excl_l[b*T + t] = el;
      excl_i[b*T + t] = ei;
    }
  }
}

// ---------------- GEMM: h[hrows,768](bf16) = x @ W^T ----------------
__global__ __launch_bounds__(256) void gemm_kernel(const void* __restrict__ At, int arow0,
                                                   const u16* __restrict__ As,
                                                   const u16* __restrict__ Bw,
                                                   u16* __restrict__ C,
                                                   int text_tiles, int ctext,
                                                   int forceBf,
                                                   const int* __restrict__ flagp){
  __shared__ __align__(16) u16 lA[128*72];
  __shared__ __align__(16) u16 lB[128*72];
  int isF32 = forceBf ? 0 : *flagp;
  int tid = threadIdx.x;

  // 1-D grid, XCD-aware bijective swizzle so the 6 col-tiles sharing an
  // A-panel (consecutive logical ids) land on the same XCD's L2.
  int nb = gridDim.x;
  int bid = blockIdx.x;
  int q = nb >> 3, r = nb & 7;
  int xcd = bid & 7, ixx = bid >> 3;
  int lid = (xcd < r ? xcd*(q+1) : r*(q+1) + (xcd - r)*q) + ixx;
  int tile = lid / 6;
  int nbase = (lid % 6) * 128;

  bool spec = (tile >= text_tiles);
  int lrow0 = spec ? (tile - text_tiles)*128 : tile*128;
  int crow0 = spec ? (ctext + lrow0) : lrow0;
  const u16*   Abf = spec ? (As + (size_t)lrow0*H)
                          : ((const u16*)At + (size_t)(arow0 + lrow0)*H);
  const float* Af  = (const float*)At + (size_t)(arow0 + lrow0)*H;
  int wave = tid >> 6, lane = tid & 63;
  int wm = (wave >> 1) * 64, wn = (wave & 1) * 64;
  int lrow = lane & 15, lkq = (lane >> 4) * 8;
  int r0 = tid >> 3;
  int c0 = (tid & 7) * 8;

  floatx4 acc[4][4];
  #pragma unroll
  for (int i = 0; i < 4; i++)
    #pragma unroll
    for (int j = 0; j < 4; j++)
      acc[i][j] = (floatx4){0.f,0.f,0.f,0.f};

  for (int k0 = 0; k0 < H; k0 += 64){
    short8 va[4], vb[4];
    #pragma unroll
    for (int i = 0; i < 4; i++){
      int row = i*32 + r0;
      if (spec || !isF32) va[i] = *(const short8*)(Abf + (size_t)row*H + k0 + c0);
      else {
        const float* p = Af + (size_t)row*H + k0 + c0;
        float4 lo = *(const float4*)p;
        float4 hi = *(const float4*)(p + 4);
        short8 tv;
        tv[0]=(short)f2bf(lo.x); tv[1]=(short)f2bf(lo.y); tv[2]=(short)f2bf(lo.z); tv[3]=(short)f2bf(lo.w);
        tv[4]=(short)f2bf(hi.x); tv[5]=(short)f2bf(hi.y); tv[6]=(short)f2bf(hi.z); tv[7]=(short)f2bf(hi.w);
        va[i] = tv;
      }
      vb[i] = *(const short8*)(Bw + (size_t)(nbase + row)*H + k0 + c0);
    }
    __syncthreads();
    #pragma unroll
    for (int i = 0; i < 4; i++){
      int row = i*32 + r0;
      *(short8*)(lA + row*72 + c0) = va[i];
      *(short8*)(lB + row*72 + c0) = vb[i];
    }
    __syncthreads();
    #pragma unroll
    for (int kk = 0; kk < 2; kk++){
      short8 af[4], bfv[4];
      #pragma unroll
      for (int i = 0; i < 4; i++){
        af[i]  = *(const short8*)(lA + (wm + i*16 + lrow)*72 + kk*32 + lkq);
        bfv[i] = *(const short8*)(lB + (wn + i*16 + lrow)*72 + kk*32 + lkq);
      }
      #pragma unroll
      for (int i = 0; i < 4; i++)
        #pragma unroll
        for (int j = 0; j < 4; j++)
          acc[i][j] = __builtin_amdgcn_mfma_f32_16x16x32_bf16(af[i], bfv[j], acc[i][j], 0, 0, 0);
    }
  }
  int qrow = (lane >> 4) * 4;
  int col = lane & 15;
  #pragma unroll
  for (int i = 0; i < 4; i++)
    #pragma unroll
    for (int j = 0; j < 4; j++)
      #pragma unroll
      for (int r2 = 0; r2 < 4; r2++){
        int grow = crow0 + wm + i*16 + qrow + r2;
        int gcol = nbase + wn + j*16 + col;
        C[(size_t)grow*H + gcol] = f2bf(acc[i][j][r2]);
      }
}

// ---------------- per-node es/ed v2: wave-per-node, all 64 lanes active ----------------
__global__ __launch_bounds__(256) void node_att_kernel(const u16* __restrict__ h,
                                                       const u16* __restrict__ a_s,
                                                       const u16* __restrict__ a_d,
                                                       float* __restrict__ es,
                                                       float* __restrict__ ed,
                                                       int nnodes){
  int tid = threadIdx.x, wave = tid >> 6, lane = tid & 63;
  int node = blockIdx.x*4 + wave;
  if (node >= nnodes) return;
  int head = lane >> 4, i16 = lane & 15;
  int off = head*DOUT + i16*12;
  const u16* hp = h + (size_t)node*H + off;
  float s = 0.f, d = 0.f;
  #pragma unroll
  for (int k = 0; k < 3; k++){
    s4v hv = *(const s4v*)(hp + k*4);
    s4v sv = *(const s4v*)(a_s + off + k*4);
    s4v dv = *(const s4v*)(a_d + off + k*4);
    #pragma unroll
    for (int c = 0; c < 4; c++){
      float hf = bf2f((u16)hv[c]);
      s += hf * bf2f((u16)sv[c]);
      d += hf * bf2f((u16)dv[c]);
    }
  }
  #pragma unroll
  for (int o = 8; o > 0; o >>= 1){ s += __shfl_down(s, o); d += __shfl_down(d, o); }
  if (i16 == 0){ es[node*4 + head] = s; ed[node*4 + head] = d; }
}

// ---------------- attention, text destinations (wave-per-node, XCD swizzle) ----------------
__global__ __launch_bounds__(256) void attn_text_kernel(
    const u16* __restrict__ h,
    const u16* __restrict__ xres,        // bf16 residual source (when resBf)
    const void* __restrict__ xraw,       // raw residual source (when !resBf)
    int xrow0,
    void* __restrict__ xout,             // d_out (when outRaw)
    u16* __restrict__ xoutbf,            // xint (when !outRaw)
    const float* __restrict__ es, const float* __restrict__ ed,
    const int* __restrict__ exl_c, const int* __restrict__ exi_c,
    const u16* __restrict__ bias, const u16* __restrict__ gamma, const u16* __restrict__ beta,
    int ctext, int resBf, int outRaw, const int* __restrict__ flagp){
  __shared__ float alpha_l[4][9][4];

  int isF32 = *flagp;
  int tid = threadIdx.x, wave = tid >> 6, lane = tid & 63;

  // XCD-aware bijective swizzle (contiguous logical chunk per XCD)
  int nb = gridDim.x;
  int bid = blockIdx.x;
  int q = nb >> 3, r = nb & 7;
  int xcd = bid & 7, ixx = bid >> 3;
  int lb = (xcd < r ? xcd*(q+1) : r*(q+1) + (xcd - r)*q) + ixx;

  int loc = lb*4 + wave;
  int bloc = loc >> 9, t = loc & 511;
  int el = exl_c[loc], ei = exi_c[loc];
  int sbase = ctext + bloc*8;

  // wave-parallel softmax: lane = e*4 + hh (36 active lanes)
  int e = lane >> 2, hh = lane & 3;
  bool act = (e < 9) && !(e == 1 && t == 0) && !(e == 2 && t == T-1);
  int srcE;
  if (e == 0)      srcE = loc;
  else if (e == 1) srcE = loc - 1;
  else if (e == 2) srcE = loc + 1;
  else if (e < 6){ int k = e - 3; srcE = sbase + k + (k >= el ? 1 : 0); }
  else           { int k = e - 6; srcE = sbase + 4 + (k & 3) + ((k & 3) >= ei ? 1 : 0); }
  float v = -1e30f;
  if (act) v = lrelu(es[srcE*4 + hh] + ed[loc*4 + hh]);
  float m = v;
  #pragma unroll
  for (int o = 4; o < 64; o <<= 1) m = fmaxf(m, __shfl_xor(m, o));
  float w = act ? expf(fminf(v - m, 0.f)) : 0.f;
  float den = w;
  #pragma unroll
  for (int o = 4; o < 64; o <<= 1) den += __shfl_xor(den, o);
  if (e < 9) alpha_l[wave][e][hh] = w / (den + 1e-16f);
  __syncthreads();

  // source ids (compile-time indexed only)
  int srcs[9];
  srcs[0] = loc;
  srcs[1] = (t > 0)   ? loc - 1 : loc;
  srcs[2] = (t < T-1) ? loc + 1 : loc;
  #pragma unroll
  for (int k = 0; k < 3; k++){
    srcs[3+k] = sbase + k + (k >= el ? 1 : 0);
    srcs[6+k] = sbase + 4 + k + (k >= ei ? 1 : 0);
  }

  // aggregation: lane owns 3 chunks of 4 contiguous dims
  int d0 = lane*4;
  int hk0 = d0/DOUT, hk1 = (d0+256)/DOUT, hk2 = (d0+512)/DOUT;
  float a0[4] = {0,0,0,0}, a1[4] = {0,0,0,0}, a2[4] = {0,0,0,0};
  #pragma unroll
  for (int ee = 0; ee < 9; ee++){
    const u16* hp = h + (size_t)srcs[ee]*H + d0;
    s4v v0 = *(const s4v*)(hp);
    s4v v1 = *(const s4v*)(hp + 256);
    s4v v2 = *(const s4v*)(hp + 512);
    float al0 = alpha_l[wave][ee][hk0];
    float al1 = alpha_l[wave][ee][hk1];
    float al2 = alpha_l[wave][ee][hk2];
    #pragma unroll
    for (int c = 0; c < 4; c++){
      a0[c] += al0 * bf2f((u16)v0[c]);
      a1[c] += al1 * bf2f((u16)v1[c]);
      a2[c] += al2 * bf2f((u16)v2[c]);
    }
  }

  // bias + relu + residual + LN (in-wave butterfly)
  size_t xoff = (size_t)(xrow0 + loc)*H + d0;
  s4v b0 = *(const s4v*)(bias + d0);
  s4v b1 = *(const s4v*)(bias + d0 + 256);
  s4v b2 = *(const s4v*)(bias + d0 + 512);
  float xr0[4], xr1[4], xr2[4];
  if (resBf){
    const u16* xp = xres + xoff;
    s4v x0 = *(const s4v*)xp;
    s4v x1 = *(const s4v*)(xp + 256);
    s4v x2 = *(const s4v*)(xp + 512);
    #pragma unroll
    for (int c = 0; c < 4; c++){
      xr0[c] = bf2f((u16)x0[c]); xr1[c] = bf2f((u16)x1[c]); xr2[c] = bf2f((u16)x2[c]);
    }
  } else if (isF32){
    const float* xp = (const float*)xraw + xoff;
    float4 x0 = *(const float4*)xp;
    float4 x1 = *(const float4*)(xp + 256);
    float4 x2 = *(const float4*)(xp + 512);
    xr0[0]=x0.x; xr0[1]=x0.y; xr0[2]=x0.z; xr0[3]=x0.w;
    xr1[0]=x1.x; xr1[1]=x1.y; xr1[2]=x1.z; xr1[3]=x1.w;
    xr2[0]=x2.x; xr2[1]=x2.y; xr2[2]=x2.z; xr2[3]=x2.w;
  } else {
    const u16* xp = (const u16*)xraw + xoff;
    s4v x0 = *(const s4v*)xp;
    s4v x1 = *(const s4v*)(xp + 256);
    s4v x2 = *(const s4v*)(xp + 512);
    #pragma unroll
    for (int c = 0; c < 4; c++){
      xr0[c] = bf2f((u16)x0[c]); xr1[c] = bf2f((u16)x1[c]); xr2[c] = bf2f((u16)x2[c]);
    }
  }
  float y0[4], y1[4], y2[4];
  float sum = 0.f, sumsq = 0.f;
  #pragma unroll
  for (int c = 0; c < 4; c++){
    y0[c] = fmaxf(a0[c] + bf2f((u16)b0[c]), 0.f) + xr0[c];
    y1[c] = fmaxf(a1[c] + bf2f((u16)b1[c]), 0.f) + xr1[c];
    y2[c] = fmaxf(a2[c] + bf2f((u16)b2[c]), 0.f) + xr2[c];
    sum   += y0[c] + y1[c] + y2[c];
    sumsq += y0[c]*y0[c] + y1[c]*y1[c] + y2[c]*y2[c];
  }
  #pragma unroll
  for (int o = 1; o < 64; o <<= 1){
    sum   += __shfl_xor(sum, o);
    sumsq += __shfl_xor(sumsq, o);
  }
  float mean = sum * (1.f/H);
  float var = sumsq * (1.f/H) - mean*mean;
  float rstd = rsqrtf(fmaxf(var, 0.f) + 1e-5f);
  s4v g0 = *(const s4v*)(gamma + d0);
  s4v g1 = *(const s4v*)(gamma + d0 + 256);
  s4v g2 = *(const s4v*)(gamma + d0 + 512);
  s4v be0 = *(const s4v*)(beta + d0);
  s4v be1 = *(const s4v*)(beta + d0 + 256);
  s4v be2 = *(const s4v*)(beta + d0 + 512);
  float o0[4], o1[4], o2[4];
  #pragma unroll
  for (int c = 0; c < 4; c++){
    o0[c] = (y0[c] - mean) * rstd * bf2f((u16)g0[c]) + bf2f((u16)be0[c]);
    o1[c] = (y1[c] - mean) * rstd * bf2f((u16)g1[c]) + bf2f((u16)be1[c]);
    o2[c] = (y2[c] - mean) * rstd * bf2f((u16)g2[c]) + bf2f((u16)be2[c]);
  }
  if (!outRaw){
    u16* xo = xoutbf + xoff;
    s4v w0, w1, w2;
    #pragma unroll
    for (int c = 0; c < 4; c++){
      w0[c] = (short)f2bf(o0[c]); w1[c] = (short)f2bf(o1[c]); w2[c] = (short)f2bf(o2[c]);
    }
    *(s4v*)xo = w0; *(s4v*)(xo + 256) = w1; *(s4v*)(xo + 512) = w2;
  } else if (isF32){
    float* xo = (float*)xout + xoff;
    float4 w0, w1, w2;
    w0.x=o0[0]; w0.y=o0[1]; w0.z=o0[2]; w0.w=o0[3];
    w1.x=o1[0]; w1.y=o1[1]; w1.z=o1[2]; w1.w=o1[3];
    w2.x=o2[0]; w2.y=o2[1]; w2.z=o2[2]; w2.w=o2[3];
    *(float4*)xo = w0; *(float4*)(xo + 256) = w1; *(float4*)(xo + 512) = w2;
  } else {
    u16* xo = (u16*)xout + xoff;
    s4v w0, w1, w2;
    #pragma unroll
    for (int c = 0; c < 4; c++){
      w0[c] = (short)f2bf(o0[c]); w1[c] = (short)f2bf(o1[c]); w2[c] = (short)f2bf(o2[c]);
    }
    *(s4v*)xo = w0; *(s4v*)(xo + 256) = w1; *(s4v*)(xo + 512) = w2;
  }
}

// ---------------- attention, special destinations: one block per (batch,special) ----------------
__global__ __launch_bounds__(256) void attn_spec_kernel(
    const u16* __restrict__ h, u16* __restrict__ xs_c,
    const float* __restrict__ es, const float* __restrict__ ed,
    const int* __restrict__ exl_c, const int* __restrict__ exi_c,
    const u16* __restrict__ bias, const u16* __restrict__ gamma, const u16* __restrict__ beta,
    int ctext){
  __shared__ float wred[16];
  __shared__ float wdyn[512][4];
  __shared__ float sw[8][4];
  __shared__ float wm4[4][4], wsum4[4][4];

  int tid = threadIdx.x, wave = tid >> 6, lane = tid & 63;

  int idx = blockIdx.x;
  int bloc = idx >> 3, s = idx & 7;
  int node = ctext + idx;
  const int* excl = (s < 4) ? exl_c : exi_c;
  int target = s & 3;
  float edv[4];
  #pragma unroll
  for (int hh = 0; hh < 4; hh++) edv[hh] = ed[node*4 + hh];

  int t0 = tid, t1 = tid + 256;
  bool sel0 = (excl[bloc*512 + t0] != target);
  bool sel1 = (excl[bloc*512 + t1] != target);
  const float* e0 = es + (size_t)(bloc*512 + t0)*4;
  const float* e1 = es + (size_t)(bloc*512 + t1)*4;
  float v0[4], v1[4], vs[4], m[4];
  #pragma unroll
  for (int hh = 0; hh < 4; hh++){
    v0[hh] = sel0 ? lrelu(e0[hh] + edv[hh]) : -1e30f;
    v1[hh] = sel1 ? lrelu(e1[hh] + edv[hh]) : -1e30f;
    m[hh] = fmaxf(v0[hh], v1[hh]);
  }
  if (tid < 8){
    const float* ep = es + (size_t)(ctext + bloc*8 + tid)*4;
    #pragma unroll
    for (int hh = 0; hh < 4; hh++){ vs[hh] = lrelu(ep[hh] + edv[hh]); m[hh] = fmaxf(m[hh], vs[hh]); }
  }
  #pragma unroll
  for (int hh = 0; hh < 4; hh++)
    for (int o = 32; o > 0; o >>= 1) m[hh] = fmaxf(m[hh], __shfl_down(m[hh], o));
  if (lane == 0){
    #pragma unroll
    for (int hh = 0; hh < 4; hh++) wm4[wave][hh] = m[hh];
  }
  __syncthreads();
  #pragma unroll
  for (int hh = 0; hh < 4; hh++)
    m[hh] = fmaxf(fmaxf(wm4[0][hh], wm4[1][hh]), fmaxf(wm4[2][hh], wm4[3][hh]));

  float ds[4];
  #pragma unroll
  for (int hh = 0; hh < 4; hh++){
    float w0 = sel0 ? expf(fminf(v0[hh] - m[hh], 0.f)) : 0.f;
    float w1 = sel1 ? expf(fminf(v1[hh] - m[hh], 0.f)) : 0.f;
    wdyn[t0][hh] = w0; wdyn[t1][hh] = w1;
    ds[hh] = w0 + w1;
  }
  if (tid < 8){
    #pragma unroll
    for (int hh = 0; hh < 4; hh++){
      float w = expf(fminf(vs[hh] - m[hh], 0.f));
      sw[tid][hh] = w; ds[hh] += w;
    }
  }
  #pragma unroll
  for (int hh = 0; hh < 4; hh++)
    for (int o = 32; o > 0; o >>= 1) ds[hh] += __shfl_down(ds[hh], o);
  if (lane == 0){
    #pragma unroll
    for (int hh = 0; hh < 4; hh++) wsum4[wave][hh] = ds[hh];
  }
  __syncthreads();   // also makes wdyn/sw visible

  // aggregation: thread cc<192 owns 4 contiguous dims, vectorized short4 loads
  int cc = tid;
  int hh4 = (cc < 192) ? (cc/48) : 0;
  float dinv = 1.f / (wsum4[0][hh4] + wsum4[1][hh4] + wsum4[2][hh4] + wsum4[3][hh4] + 1e-16f);
  float agg[4] = {0.f, 0.f, 0.f, 0.f};
  if (cc < 192){
    const u16* hp = h + (size_t)(bloc*512)*H + cc*4;
    #pragma unroll 8
    for (int tt = 0; tt < 512; tt++){
      s4v hv = *(const s4v*)(hp + (size_t)tt*H);
      float wv = wdyn[tt][hh4];
      agg[0] += wv * bf2f((u16)hv[0]);
      agg[1] += wv * bf2f((u16)hv[1]);
      agg[2] += wv * bf2f((u16)hv[2]);
      agg[3] += wv * bf2f((u16)hv[3]);
    }
    #pragma unroll
    for (int e2 = 0; e2 < 8; e2++){
      s4v hv = *(const s4v*)(h + (size_t)(ctext + bloc*8 + e2)*H + cc*4);
      float wv = sw[e2][hh4];
      agg[0] += wv * bf2f((u16)hv[0]);
      agg[1] += wv * bf2f((u16)hv[1]);
      agg[2] += wv * bf2f((u16)hv[2]);
      agg[3] += wv * bf2f((u16)hv[3]);
    }
  }
  float y[4] = {0.f,0.f,0.f,0.f};
  float sum = 0.f, sumsq = 0.f;
  if (cc < 192){
    s4v bv = *(const s4v*)(bias + cc*4);
    s4v xv = *(const s4v*)(xs_c + (size_t)idx*H + cc*4);
    #pragma unroll
    for (int c = 0; c < 4; c++){
      float a = agg[c] * dinv;
      float o = fmaxf(a + bf2f((u16)bv[c]), 0.f);
      float yv = o + bf2f((u16)xv[c]);
      y[c] = yv; sum += yv; sumsq += yv*yv;
    }
  }
  for (int o = 32; o > 0; o >>= 1){ sum += __shfl_down(sum, o); sumsq += __shfl_down(sumsq, o); }
  if (lane == 0){ wred[wave] = sum; wred[8 + wave] = sumsq; }
  __syncthreads();
  sum   = wred[0] + wred[1] + wred[2] + wred[3];
  sumsq = wred[8] + wred[9] + wred[10] + wred[11];
  float mean = sum * (1.f/H);
  float var = sumsq * (1.f/H) - mean*mean;
  float rstd = rsqrtf(fmaxf(var, 0.f) + 1e-5f);
  if (cc < 192){
    s4v gv = *(const s4v*)(gamma + cc*4);
    s4v bev = *(const s4v*)(beta + cc*4);
    s4v wv;
    #pragma unroll
    for (int c = 0; c < 4; c++){
      float o = (y[c] - mean) * rstd * bf2f((u16)gv[c]) + bf2f((u16)bev[c]);
      wv[c] = (short)f2bf(o);
    }
    *(s4v*)(xs_c + (size_t)idx*H + cc*4) = wv;
  }
}

extern "C" void kernel_launch(void* const* d_in, const int* in_sizes, int n_in,
                              void* d_out, int out_size, void* d_ws, size_t ws_size,
                              hipStream_t stream){
  const void* text  = d_in[0];
  const void* label = d_in[1];
  const void* image = d_in[2];

  auto align256 = [](size_t x){ return (x + 255) & ~(size_t)255; };
  auto baseNeed = [&](int cand) -> size_t {
    int ct = MTEXT/cand, cs = MSPEC/cand;
    int st = (cs + 127)/128;
    size_t hr = (size_t)ct + (size_t)st*128;
    return align256(4)
         + align256(hr*H*2)
         + align256((size_t)(MSPEC+64)*H*2)
         + 2*align256((size_t)MTEXT*4)
         + align256((size_t)MSPEC*4)
         + 2*align256(hr*4*4)
         + align256((size_t)3*H*H*2)
         + 5*align256((size_t)3*H*2);
  };
  size_t bfExtra = 2*align256((size_t)MTEXT*H*2);   // xt_bf + xint

  // deterministic config from ws_size (graph-safe)
  int useBf = 0, nch = 8;
  for (int cand = 1; cand <= 8; cand <<= 1){
    if (baseNeed(cand) + bfExtra <= ws_size){ useBf = 1; nch = cand; break; }
  }
  if (!useBf){
    for (int cand = 1; cand <= 8; cand <<= 1){
      if (baseNeed(cand) <= ws_size || cand == 8){ nch = cand; break; }
    }
  }
  int ctext = MTEXT/nch, cspec = MSPEC/nch;
  int spec_tiles = (cspec + 127)/128;
  int hrows = ctext + spec_tiles*128;
  int text_tiles = ctext / 128;

  char* ws = (char*)d_ws;
  size_t off = 0;
  auto alloc = [&](size_t bytes) -> void* {
    void* p = ws + off; off += (bytes + 255) & ~(size_t)255; return p;
  };
  int*   flag = (int*)  alloc(4);
  u16*   h    = (u16*)  alloc((size_t)hrows*H*2);
  u16*   xs   = (u16*)  alloc((size_t)(MSPEC+64)*H*2);
  int*   exl  = (int*)  alloc((size_t)MTEXT*4);
  int*   exi  = (int*)  alloc((size_t)MTEXT*4);
  float* nrm  = (float*)alloc((size_t)MSPEC*4);
  float* es   = (float*)alloc((size_t)hrows*4*4);
  float* ed   = (float*)alloc((size_t)hrows*4*4);
  u16*   Wc   = (u16*)  alloc((size_t)3*H*H*2);
  u16*   asc  = (u16*)  alloc((size_t)3*H*2);
  u16*   adc  = (u16*)  alloc((size_t)3*H*2);
  u16*   bc   = (u16*)  alloc((size_t)3*H*2);
  u16*   gc   = (u16*)  alloc((size_t)3*H*2);
  u16*   bec  = (u16*)  alloc((size_t)3*H*2);
  u16*   xt_bf = nullptr;
  u16*   xint  = nullptr;
  if (useBf){
    xt_bf = (u16*)alloc((size_t)MTEXT*H*2);
    xint  = (u16*)alloc((size_t)MTEXT*H*2);
  }

  detect_kernel<<<1, 256, 0, stream>>>((const u16*)text, flag);
  convert_kernel<<<(3*H*H + 255)/256, 256, 0, stream>>>(d_in[3], Wc, 3*H*H, flag);
  convert_kernel<<<9, 256, 0, stream>>>(d_in[4], asc, 3*H, flag);
  convert_kernel<<<9, 256, 0, stream>>>(d_in[5], adc, 3*H, flag);
  convert_kernel<<<9, 256, 0, stream>>>(d_in[6], bc,  3*H, flag);
  convert_kernel<<<9, 256, 0, stream>>>(d_in[7], gc,  3*H, flag);
  convert_kernel<<<9, 256, 0, stream>>>(d_in[8], bec, 3*H, flag);

  prep_spec_kernel<<<MSPEC, 256, 0, stream>>>(label, image, xs, nrm, flag);
  topk_kernel<<<dim3(T/16, B), 256, 0, stream>>>(text, label, image, nrm, exl, exi, flag);
  if (useBf)
    convert_text_kernel<<<(MTEXT*H/4 + 255)/256, 256, 0, stream>>>(text, xt_bf, flag);

  for (int l = 0; l < 3; l++){
    const void* At; int forceBf;
    if (useBf){ At = (l == 0) ? (const void*)xt_bf : (const void*)xint; forceBf = 1; }
    else      { At = (l == 0) ? text : (const void*)d_out;              forceBf = 0; }
    const u16* xres = useBf ? ((l == 0) ? xt_bf : xint) : nullptr;
    const void* xraw = (l == 0) ? text : (const void*)d_out;
    int outRaw = (!useBf) || (l == 2);

    for (int c = 0; c < nch; c++){
      gemm_kernel<<<(text_tiles + spec_tiles)*6, 256, 0, stream>>>(
          At, c*ctext, xs + (size_t)c*cspec*H, Wc + (size_t)l*H*H, h,
          text_tiles, ctext, forceBf, flag);
      node_att_kernel<<<(ctext + cspec + 3)/4, 256, 0, stream>>>(
          h, asc + l*H, adc + l*H, es, ed, ctext + cspec);
      attn_spec_kernel<<<cspec, 256, 0, stream>>>(
          h, xs + (size_t)c*cspec*H, es, ed,
          exl + c*ctext, exi + c*ctext,
          bc + l*H, gc + l*H, bec + l*H, ctext);
      attn_text_kernel<<<ctext/4, 256, 0, stream>>>(
          h, xres, xraw, c*ctext, d_out, xint,
          es, ed, exl + c*ctext, exi + c*ctext,
          bc + l*H, gc + l*H, bec + l*H,
          ctext, useBf, outRaw, flag);
    }
  }
}

// Round 8
// 669.340 us; speedup vs baseline: 1.9815x; 1.1399x over previous
//
#include <hip/hip_runtime.h>
#include <math.h>

#define B 64
#define T 512
#define H 768
#define DOUT 192
#define MTEXT (B*T)        // 32768
#define MSPEC (B*8)        // 512

typedef unsigned short u16;
typedef __attribute__((ext_vector_type(8))) short short8;
typedef __attribute__((ext_vector_type(4))) short s4v;
typedef __attribute__((ext_vector_type(4))) float floatx4;

__device__ __forceinline__ float bf2f(u16 u){
  union { float f; unsigned int i; } v; v.i = ((unsigned int)u) << 16; return v.f;
}
__device__ __forceinline__ u16 f2bf(float f){
  unsigned int u = __float_as_uint(f);
  unsigned int lsb = (u >> 16) & 1u;
  u += 0x7fffu + lsb;
  return (u16)(u >> 16);
}
__device__ __forceinline__ float lrelu(float v){ return v > 0.f ? v : 0.2f*v; }
__device__ __forceinline__ float ldv(const void* p, size_t i, int isF32){
  return isF32 ? ((const float*)p)[i] : bf2f(((const u16*)p)[i]);
}

// ---------------- detect input dtype ----------------
__global__ __launch_bounds__(256) void detect_kernel(const u16* __restrict__ raw, int* __restrict__ flag){
  __shared__ int red[256];
  int tid = threadIdx.x;
  int cnt = 0;
  for (int i = tid; i < 2048; i += 256){
    u16 u = raw[(size_t)i*2];
    int e = (u >> 7) & 0xFF;
    if (e >= 110 && e <= 135) cnt++;
  }
  red[tid] = cnt; __syncthreads();
  for (int s = 128; s > 0; s >>= 1){ if (tid < s) red[tid] += red[tid+s]; __syncthreads(); }
  if (tid == 0) *flag = (red[0] < 1024) ? 1 : 0;   // 1 => float32 inputs
}

// ---------------- convert raw param (f32 or bf16) -> bf16 ----------------
__global__ __launch_bounds__(256) void convert_kernel(const void* __restrict__ src,
                                                      u16* __restrict__ dst, int n,
                                                      const int* __restrict__ flagp){
  int i = blockIdx.x*256 + threadIdx.x;
  if (i >= n) return;
  if (*flagp) dst[i] = f2bf(((const float*)src)[i]);
  else        dst[i] = ((const u16*)src)[i];
}

// ---------------- convert text -> bf16 (vectorized, 4 elems/thread) ----------------
__global__ __launch_bounds__(256) void convert_text_kernel(const void* __restrict__ src,
                                                           u16* __restrict__ dst,
                                                           const int* __restrict__ flagp){
  size_t i = (size_t)blockIdx.x*256 + threadIdx.x;   // one group of 4 elems
  if (*flagp){
    float4 v = ((const float4*)src)[i];
    s4v o;
    o[0] = (short)f2bf(v.x); o[1] = (short)f2bf(v.y);
    o[2] = (short)f2bf(v.z); o[3] = (short)f2bf(v.w);
    ((s4v*)dst)[i] = o;
  } else {
    ((s4v*)dst)[i] = ((const s4v*)src)[i];
  }
}

// ---------------- prep specials: label/image -> xs (bf16) + sq-norms ----------------
__global__ __launch_bounds__(256) void prep_spec_kernel(const void* __restrict__ label,
                                                        const void* __restrict__ image,
                                                        u16* __restrict__ xs,
                                                        float* __restrict__ norms2,
                                                        const int* __restrict__ flagp){
  __shared__ float red[256];
  int isF32 = *flagp;
  int rr = blockIdx.x;          // 0..511
  int tid = threadIdx.x;
  int b = rr >> 3, s = rr & 7;
  const void* srcb = (s < 4) ? label : image;
  size_t base = (size_t)(b*4 + (s & 3))*H;
  float sq = 0.f;
  #pragma unroll
  for (int r = 0; r < 3; r++){
    int dd = tid + r*256;
    float f = ldv(srcb, base + dd, isF32);
    xs[(size_t)rr*H + dd] = f2bf(f);
    sq += f*f;
  }
  red[tid] = sq; __syncthreads();
  for (int ss = 128; ss > 0; ss >>= 1){ if (tid < ss) red[tid] += red[tid+ss]; __syncthreads(); }
  if (tid == 0) norms2[rr] = red[0];
}

// ---------------- topk v2: LDS-staged specials, 16 text rows per block ----------------
__global__ __launch_bounds__(256) void topk_kernel(const void* __restrict__ text,
                                                   const void* __restrict__ label,
                                                   const void* __restrict__ image,
                                                   const float* __restrict__ norms2,
                                                   int* __restrict__ excl_l,
                                                   int* __restrict__ excl_i,
                                                   const int* __restrict__ flagp){
  __shared__ float spec[8*H];            // 24 KB
  int isF32 = *flagp;
  int tid = threadIdx.x, wave = tid >> 6, lane = tid & 63;
  int b = blockIdx.y;

  // stage 8 special rows (4 label + 4 image) into LDS as f32
  if (isF32){
    const float* lb = (const float*)label + (size_t)b*4*H;
    const float* im = (const float*)image + (size_t)b*4*H;
    #pragma unroll
    for (int j = 0; j < 6; j++){
      int idx = tid + j*256;             // float4 index, 0..1535
      int flat = idx*4;
      int s = flat / H, d = flat % H;
      const float* src = (s < 4) ? (lb + (size_t)s*H + d) : (im + (size_t)(s-4)*H + d);
      *(float4*)(spec + s*H + d) = *(const float4*)src;
    }
  } else {
    const u16* lb = (const u16*)label + (size_t)b*4*H;
    const u16* im = (const u16*)image + (size_t)b*4*H;
    #pragma unroll
    for (int j = 0; j < 6; j++){
      int idx = tid + j*256;
      int flat = idx*4;
      int s = flat / H, d = flat % H;
      const u16* src = (s < 4) ? (lb + (size_t)s*H + d) : (im + (size_t)(s-4)*H + d);
      s4v v = *(const s4v*)src;
      float4 f;
      f.x = bf2f((u16)v[0]); f.y = bf2f((u16)v[1]);
      f.z = bf2f((u16)v[2]); f.w = bf2f((u16)v[3]);
      *(float4*)(spec + s*H + d) = f;
    }
  }
  __syncthreads();

  #pragma unroll
  for (int pass = 0; pass < 4; pass++){
    int t = blockIdx.x*16 + pass*4 + wave;
    size_t tb = ((size_t)b*T + t)*H;
    float tx[12];
    if (isF32){
      const float* tp = (const float*)text + tb;
      #pragma unroll
      for (int k = 0; k < 3; k++){
        float4 v = *(const float4*)(tp + lane*4 + k*256);
        tx[k*4+0]=v.x; tx[k*4+1]=v.y; tx[k*4+2]=v.z; tx[k*4+3]=v.w;
      }
    } else {
      const u16* tp = (const u16*)text + tb;
      #pragma unroll
      for (int k = 0; k < 3; k++){
        s4v v = *(const s4v*)(tp + lane*4 + k*256);
        tx[k*4+0]=bf2f((u16)v[0]); tx[k*4+1]=bf2f((u16)v[1]);
        tx[k*4+2]=bf2f((u16)v[2]); tx[k*4+3]=bf2f((u16)v[3]);
      }
    }
    float dot[8] = {0,0,0,0,0,0,0,0};
    #pragma unroll
    for (int k = 0; k < 3; k++){
      int d = lane*4 + k*256;
      #pragma unroll
      for (int s = 0; s < 8; s++){
        float4 sv = *(const float4*)(spec + s*H + d);
        dot[s] += tx[k*4+0]*sv.x + tx[k*4+1]*sv.y + tx[k*4+2]*sv.z + tx[k*4+3]*sv.w;
      }
    }
    #pragma unroll
    for (int s = 0; s < 8; s++)
      for (int o = 32; o > 0; o >>= 1) dot[s] += __shfl_down(dot[s], o);
    if (lane == 0){
      float vl[4], vi[4];
      #pragma unroll
      for (int j = 0; j < 4; j++){
        vl[j] = dot[j]   / fmaxf(sqrtf(norms2[b*8 + j]),     1e-8f);
        vi[j] = dot[4+j] / fmaxf(sqrtf(norms2[b*8 + 4 + j]), 1e-8f);
      }
      int el = 0, ei = 0;
      #pragma unroll
      for (int j = 1; j < 4; j++){
        if (vl[j] <= vl[el]) el = j;
        if (vi[j] <= vi[ei]) ei = j;
      }
      excl_l[b*T + t] = el;
      excl_i[b*T + t] = ei;
    }
  }
}

// ---------------- GEMM: h[hrows,768](bf16) = x @ W^T ----------------
__global__ __launch_bounds__(256) void gemm_kernel(const void* __restrict__ At, int arow0,
                                                   const u16* __restrict__ As,
                                                   const u16* __restrict__ Bw,
                                                   u16* __restrict__ C,
                                                   int text_tiles, int ctext,
                                                   int forceBf,
                                                   const int* __restrict__ flagp){
  __shared__ __align__(16) u16 lA[128*72];
  __shared__ __align__(16) u16 lB[128*72];
  int isF32 = forceBf ? 0 : *flagp;
  int tid = threadIdx.x;

  // 1-D grid, XCD-aware bijective swizzle so the 6 col-tiles sharing an
  // A-panel (consecutive logical ids) land on the same XCD's L2.
  int nb = gridDim.x;
  int bid = blockIdx.x;
  int q = nb >> 3, r = nb & 7;
  int xcd = bid & 7, ixx = bid >> 3;
  int lid = (xcd < r ? xcd*(q+1) : r*(q+1) + (xcd - r)*q) + ixx;
  int tile = lid / 6;
  int nbase = (lid % 6) * 128;

  bool spec = (tile >= text_tiles);
  int lrow0 = spec ? (tile - text_tiles)*128 : tile*128;
  int crow0 = spec ? (ctext + lrow0) : lrow0;
  const u16*   Abf = spec ? (As + (size_t)lrow0*H)
                          : ((const u16*)At + (size_t)(arow0 + lrow0)*H);
  const float* Af  = (const float*)At + (size_t)(arow0 + lrow0)*H;
  int wave = tid >> 6, lane = tid & 63;
  int wm = (wave >> 1) * 64, wn = (wave & 1) * 64;
  int lrow = lane & 15, lkq = (lane >> 4) * 8;
  int r0 = tid >> 3;
  int c0 = (tid & 7) * 8;

  floatx4 acc[4][4];
  #pragma unroll
  for (int i = 0; i < 4; i++)
    #pragma unroll
    for (int j = 0; j < 4; j++)
      acc[i][j] = (floatx4){0.f,0.f,0.f,0.f};

  for (int k0 = 0; k0 < H; k0 += 64){
    short8 va[4], vb[4];
    #pragma unroll
    for (int i = 0; i < 4; i++){
      int row = i*32 + r0;
      if (spec || !isF32) va[i] = *(const short8*)(Abf + (size_t)row*H + k0 + c0);
      else {
        const float* p = Af + (size_t)row*H + k0 + c0;
        float4 lo = *(const float4*)p;
        float4 hi = *(const float4*)(p + 4);
        short8 tv;
        tv[0]=(short)f2bf(lo.x); tv[1]=(short)f2bf(lo.y); tv[2]=(short)f2bf(lo.z); tv[3]=(short)f2bf(lo.w);
        tv[4]=(short)f2bf(hi.x); tv[5]=(short)f2bf(hi.y); tv[6]=(short)f2bf(hi.z); tv[7]=(short)f2bf(hi.w);
        va[i] = tv;
      }
      vb[i] = *(const short8*)(Bw + (size_t)(nbase + row)*H + k0 + c0);
    }
    __syncthreads();
    #pragma unroll
    for (int i = 0; i < 4; i++){
      int row = i*32 + r0;
      *(short8*)(lA + row*72 + c0) = va[i];
      *(short8*)(lB + row*72 + c0) = vb[i];
    }
    __syncthreads();
    #pragma unroll
    for (int kk = 0; kk < 2; kk++){
      short8 af[4], bfv[4];
      #pragma unroll
      for (int i = 0; i < 4; i++){
        af[i]  = *(const short8*)(lA + (wm + i*16 + lrow)*72 + kk*32 + lkq);
        bfv[i] = *(const short8*)(lB + (wn + i*16 + lrow)*72 + kk*32 + lkq);
      }
      #pragma unroll
      for (int i = 0; i < 4; i++)
        #pragma unroll
        for (int j = 0; j < 4; j++)
          acc[i][j] = __builtin_amdgcn_mfma_f32_16x16x32_bf16(af[i], bfv[j], acc[i][j], 0, 0, 0);
    }
  }
  int qrow = (lane >> 4) * 4;
  int col = lane & 15;
  #pragma unroll
  for (int i = 0; i < 4; i++)
    #pragma unroll
    for (int j = 0; j < 4; j++)
      #pragma unroll
      for (int r2 = 0; r2 < 4; r2++){
        int grow = crow0 + wm + i*16 + qrow + r2;
        int gcol = nbase + wn + j*16 + col;
        C[(size_t)grow*H + gcol] = f2bf(acc[i][j][r2]);
      }
}

// ---------------- per-node es/ed v2: wave-per-node, all 64 lanes active ----------------
__global__ __launch_bounds__(256) void node_att_kernel(const u16* __restrict__ h,
                                                       const u16* __restrict__ a_s,
                                                       const u16* __restrict__ a_d,
                                                       float* __restrict__ es,
                                                       float* __restrict__ ed,
                                                       int nnodes){
  int tid = threadIdx.x, wave = tid >> 6, lane = tid & 63;
  int node = blockIdx.x*4 + wave;
  if (node >= nnodes) return;
  int head = lane >> 4, i16 = lane & 15;
  int off = head*DOUT + i16*12;
  const u16* hp = h + (size_t)node*H + off;
  float s = 0.f, d = 0.f;
  #pragma unroll
  for (int k = 0; k < 3; k++){
    s4v hv = *(const s4v*)(hp + k*4);
    s4v sv = *(const s4v*)(a_s + off + k*4);
    s4v dv = *(const s4v*)(a_d + off + k*4);
    #pragma unroll
    for (int c = 0; c < 4; c++){
      float hf = bf2f((u16)hv[c]);
      s += hf * bf2f((u16)sv[c]);
      d += hf * bf2f((u16)dv[c]);
    }
  }
  #pragma unroll
  for (int o = 8; o > 0; o >>= 1){ s += __shfl_down(s, o); d += __shfl_down(d, o); }
  if (i16 == 0){ es[node*4 + head] = s; ed[node*4 + head] = d; }
}

// ---------------- attention, text destinations (wave-per-node, XCD swizzle) ----------------
__global__ __launch_bounds__(256) void attn_text_kernel(
    const u16* __restrict__ h,
    const u16* __restrict__ xres,        // bf16 residual source (when resBf)
    const void* __restrict__ xraw,       // raw residual source (when !resBf)
    int xrow0,
    void* __restrict__ xout,             // d_out (when outRaw)
    u16* __restrict__ xoutbf,            // xint (when !outRaw)
    const float* __restrict__ es, const float* __restrict__ ed,
    const int* __restrict__ exl_c, const int* __restrict__ exi_c,
    const u16* __restrict__ bias, const u16* __restrict__ gamma, const u16* __restrict__ beta,
    int ctext, int resBf, int outRaw, const int* __restrict__ flagp){
  __shared__ float alpha_l[4][9][4];

  int isF32 = *flagp;
  int tid = threadIdx.x, wave = tid >> 6, lane = tid & 63;

  // XCD-aware bijective swizzle (contiguous logical chunk per XCD)
  int nb = gridDim.x;
  int bid = blockIdx.x;
  int q = nb >> 3, r = nb & 7;
  int xcd = bid & 7, ixx = bid >> 3;
  int lb = (xcd < r ? xcd*(q+1) : r*(q+1) + (xcd - r)*q) + ixx;

  int loc = lb*4 + wave;
  int bloc = loc >> 9, t = loc & 511;
  int el = exl_c[loc], ei = exi_c[loc];
  int sbase = ctext + bloc*8;

  // wave-parallel softmax: lane = e*4 + hh (36 active lanes)
  int e = lane >> 2, hh = lane & 3;
  bool act = (e < 9) && !(e == 1 && t == 0) && !(e == 2 && t == T-1);
  int srcE;
  if (e == 0)      srcE = loc;
  else if (e == 1) srcE = loc - 1;
  else if (e == 2) srcE = loc + 1;
  else if (e < 6){ int k = e - 3; srcE = sbase + k + (k >= el ? 1 : 0); }
  else           { int k = e - 6; srcE = sbase + 4 + (k & 3) + ((k & 3) >= ei ? 1 : 0); }
  float v = -1e30f;
  if (act) v = lrelu(es[srcE*4 + hh] + ed[loc*4 + hh]);
  float m = v;
  #pragma unroll
  for (int o = 4; o < 64; o <<= 1) m = fmaxf(m, __shfl_xor(m, o));
  float w = act ? expf(fminf(v - m, 0.f)) : 0.f;
  float den = w;
  #pragma unroll
  for (int o = 4; o < 64; o <<= 1) den += __shfl_xor(den, o);
  if (e < 9) alpha_l[wave][e][hh] = w / (den + 1e-16f);
  __syncthreads();

  // source ids (compile-time indexed only)
  int srcs[9];
  srcs[0] = loc;
  srcs[1] = (t > 0)   ? loc - 1 : loc;
  srcs[2] = (t < T-1) ? loc + 1 : loc;
  #pragma unroll
  for (int k = 0; k < 3; k++){
    srcs[3+k] = sbase + k + (k >= el ? 1 : 0);
    srcs[6+k] = sbase + 4 + k + (k >= ei ? 1 : 0);
  }

  // aggregation: lane owns 3 chunks of 4 contiguous dims
  int d0 = lane*4;
  int hk0 = d0/DOUT, hk1 = (d0+256)/DOUT, hk2 = (d0+512)/DOUT;
  float a0[4] = {0,0,0,0}, a1[4] = {0,0,0,0}, a2[4] = {0,0,0,0};
  #pragma unroll
  for (int ee = 0; ee < 9; ee++){
    const u16* hp = h + (size_t)srcs[ee]*H + d0;
    s4v v0 = *(const s4v*)(hp);
    s4v v1 = *(const s4v*)(hp + 256);
    s4v v2 = *(const s4v*)(hp + 512);
    float al0 = alpha_l[wave][ee][hk0];
    float al1 = alpha_l[wave][ee][hk1];
    float al2 = alpha_l[wave][ee][hk2];
    #pragma unroll
    for (int c = 0; c < 4; c++){
      a0[c] += al0 * bf2f((u16)v0[c]);
      a1[c] += al1 * bf2f((u16)v1[c]);
      a2[c] += al2 * bf2f((u16)v2[c]);
    }
  }

  // bias + relu + residual + LN (in-wave butterfly)
  size_t xoff = (size_t)(xrow0 + loc)*H + d0;
  s4v b0 = *(const s4v*)(bias + d0);
  s4v b1 = *(const s4v*)(bias + d0 + 256);
  s4v b2 = *(const s4v*)(bias + d0 + 512);
  float xr0[4], xr1[4], xr2[4];
  if (resBf){
    const u16* xp = xres + xoff;
    s4v x0 = *(const s4v*)xp;
    s4v x1 = *(const s4v*)(xp + 256);
    s4v x2 = *(const s4v*)(xp + 512);
    #pragma unroll
    for (int c = 0; c < 4; c++){
      xr0[c] = bf2f((u16)x0[c]); xr1[c] = bf2f((u16)x1[c]); xr2[c] = bf2f((u16)x2[c]);
    }
  } else if (isF32){
    const float* xp = (const float*)xraw + xoff;
    float4 x0 = *(const float4*)xp;
    float4 x1 = *(const float4*)(xp + 256);
    float4 x2 = *(const float4*)(xp + 512);
    xr0[0]=x0.x; xr0[1]=x0.y; xr0[2]=x0.z; xr0[3]=x0.w;
    xr1[0]=x1.x; xr1[1]=x1.y; xr1[2]=x1.z; xr1[3]=x1.w;
    xr2[0]=x2.x; xr2[1]=x2.y; xr2[2]=x2.z; xr2[3]=x2.w;
  } else {
    const u16* xp = (const u16*)xraw + xoff;
    s4v x0 = *(const s4v*)xp;
    s4v x1 = *(const s4v*)(xp + 256);
    s4v x2 = *(const s4v*)(xp + 512);
    #pragma unroll
    for (int c = 0; c < 4; c++){
      xr0[c] = bf2f((u16)x0[c]); xr1[c] = bf2f((u16)x1[c]); xr2[c] = bf2f((u16)x2[c]);
    }
  }
  float y0[4], y1[4], y2[4];
  float sum = 0.f, sumsq = 0.f;
  #pragma unroll
  for (int c = 0; c < 4; c++){
    y0[c] = fmaxf(a0[c] + bf2f((u16)b0[c]), 0.f) + xr0[c];
    y1[c] = fmaxf(a1[c] + bf2f((u16)b1[c]), 0.f) + xr1[c];
    y2[c] = fmaxf(a2[c] + bf2f((u16)b2[c]), 0.f) + xr2[c];
    sum   += y0[c] + y1[c] + y2[c];
    sumsq += y0[c]*y0[c] + y1[c]*y1[c] + y2[c]*y2[c];
  }
  #pragma unroll
  for (int o = 1; o < 64; o <<= 1){
    sum   += __shfl_xor(sum, o);
    sumsq += __shfl_xor(sumsq, o);
  }
  float mean = sum * (1.f/H);
  float var = sumsq * (1.f/H) - mean*mean;
  float rstd = rsqrtf(fmaxf(var, 0.f) + 1e-5f);
  s4v g0 = *(const s4v*)(gamma + d0);
  s4v g1 = *(const s4v*)(gamma + d0 + 256);
  s4v g2 = *(const s4v*)(gamma + d0 + 512);
  s4v be0 = *(const s4v*)(beta + d0);
  s4v be1 = *(const s4v*)(beta + d0 + 256);
  s4v be2 = *(const s4v*)(beta + d0 + 512);
  float o0[4], o1[4], o2[4];
  #pragma unroll
  for (int c = 0; c < 4; c++){
    o0[c] = (y0[c] - mean) * rstd * bf2f((u16)g0[c]) + bf2f((u16)be0[c]);
    o1[c] = (y1[c] - mean) * rstd * bf2f((u16)g1[c]) + bf2f((u16)be1[c]);
    o2[c] = (y2[c] - mean) * rstd * bf2f((u16)g2[c]) + bf2f((u16)be2[c]);
  }
  if (!outRaw){
    u16* xo = xoutbf + xoff;
    s4v w0, w1, w2;
    #pragma unroll
    for (int c = 0; c < 4; c++){
      w0[c] = (short)f2bf(o0[c]); w1[c] = (short)f2bf(o1[c]); w2[c] = (short)f2bf(o2[c]);
    }
    *(s4v*)xo = w0; *(s4v*)(xo + 256) = w1; *(s4v*)(xo + 512) = w2;
  } else if (isF32){
    float* xo = (float*)xout + xoff;
    float4 w0, w1, w2;
    w0.x=o0[0]; w0.y=o0[1]; w0.z=o0[2]; w0.w=o0[3];
    w1.x=o1[0]; w1.y=o1[1]; w1.z=o1[2]; w1.w=o1[3];
    w2.x=o2[0]; w2.y=o2[1]; w2.z=o2[2]; w2.w=o2[3];
    *(float4*)xo = w0; *(float4*)(xo + 256) = w1; *(float4*)(xo + 512) = w2;
  } else {
    u16* xo = (u16*)xout + xoff;
    s4v w0, w1, w2;
    #pragma unroll
    for (int c = 0; c < 4; c++){
      w0[c] = (short)f2bf(o0[c]); w1[c] = (short)f2bf(o1[c]); w2[c] = (short)f2bf(o2[c]);
    }
    *(s4v*)xo = w0; *(s4v*)(xo + 256) = w1; *(s4v*)(xo + 512) = w2;
  }
}

// ---------------- attention, special destinations: one block per (batch,special) ----------------
// XCD swizzle: batch b's 8 specials land on one XCD so its L2 absorbs the 8x h-slab re-read.
__global__ __launch_bounds__(256) void attn_spec_kernel(
    const u16* __restrict__ h, u16* __restrict__ xs_c,
    const float* __restrict__ es, const float* __restrict__ ed,
    const int* __restrict__ exl_c, const int* __restrict__ exi_c,
    const u16* __restrict__ bias, const u16* __restrict__ gamma, const u16* __restrict__ beta,
    int ctext){
  __shared__ float wred[16];
  __shared__ float wdyn[512][4];
  __shared__ float sw[8][4];
  __shared__ float wm4[4][4], wsum4[4][4];

  int tid = threadIdx.x, wave = tid >> 6, lane = tid & 63;

  // XCD-aware bijective swizzle (contiguous logical chunk per XCD)
  int nb = gridDim.x;
  int bid = blockIdx.x;
  int q = nb >> 3, r = nb & 7;
  int xcd = bid & 7, ixx = bid >> 3;
  int idx = (xcd < r ? xcd*(q+1) : r*(q+1) + (xcd - r)*q) + ixx;

  int bloc = idx >> 3, s = idx & 7;
  int node = ctext + idx;
  const int* excl = (s < 4) ? exl_c : exi_c;
  int target = s & 3;
  float edv[4];
  #pragma unroll
  for (int hh = 0; hh < 4; hh++) edv[hh] = ed[node*4 + hh];

  int t0 = tid, t1 = tid + 256;
  bool sel0 = (excl[bloc*512 + t0] != target);
  bool sel1 = (excl[bloc*512 + t1] != target);
  const float* e0 = es + (size_t)(bloc*512 + t0)*4;
  const float* e1 = es + (size_t)(bloc*512 + t1)*4;
  float v0[4], v1[4], vs[4], m[4];
  #pragma unroll
  for (int hh = 0; hh < 4; hh++){
    v0[hh] = sel0 ? lrelu(e0[hh] + edv[hh]) : -1e30f;
    v1[hh] = sel1 ? lrelu(e1[hh] + edv[hh]) : -1e30f;
    m[hh] = fmaxf(v0[hh], v1[hh]);
  }
  if (tid < 8){
    const float* ep = es + (size_t)(ctext + bloc*8 + tid)*4;
    #pragma unroll
    for (int hh = 0; hh < 4; hh++){ vs[hh] = lrelu(ep[hh] + edv[hh]); m[hh] = fmaxf(m[hh], vs[hh]); }
  }
  #pragma unroll
  for (int hh = 0; hh < 4; hh++)
    for (int o = 32; o > 0; o >>= 1) m[hh] = fmaxf(m[hh], __shfl_down(m[hh], o));
  if (lane == 0){
    #pragma unroll
    for (int hh = 0; hh < 4; hh++) wm4[wave][hh] = m[hh];
  }
  __syncthreads();
  #pragma unroll
  for (int hh = 0; hh < 4; hh++)
    m[hh] = fmaxf(fmaxf(wm4[0][hh], wm4[1][hh]), fmaxf(wm4[2][hh], wm4[3][hh]));

  float ds[4];
  #pragma unroll
  for (int hh = 0; hh < 4; hh++){
    float w0 = sel0 ? expf(fminf(v0[hh] - m[hh], 0.f)) : 0.f;
    float w1 = sel1 ? expf(fminf(v1[hh] - m[hh], 0.f)) : 0.f;
    wdyn[t0][hh] = w0; wdyn[t1][hh] = w1;
    ds[hh] = w0 + w1;
  }
  if (tid < 8){
    #pragma unroll
    for (int hh = 0; hh < 4; hh++){
      float w = expf(fminf(vs[hh] - m[hh], 0.f));
      sw[tid][hh] = w; ds[hh] += w;
    }
  }
  #pragma unroll
  for (int hh = 0; hh < 4; hh++)
    for (int o = 32; o > 0; o >>= 1) ds[hh] += __shfl_down(ds[hh], o);
  if (lane == 0){
    #pragma unroll
    for (int hh = 0; hh < 4; hh++) wsum4[wave][hh] = ds[hh];
  }
  __syncthreads();   // also makes wdyn/sw visible

  // aggregation: thread cc<192 owns 4 contiguous dims, vectorized short4 loads
  int cc = tid;
  int hh4 = (cc < 192) ? (cc/48) : 0;
  float dinv = 1.f / (wsum4[0][hh4] + wsum4[1][hh4] + wsum4[2][hh4] + wsum4[3][hh4] + 1e-16f);
  float agg[4] = {0.f, 0.f, 0.f, 0.f};
  if (cc < 192){
    const u16* hp = h + (size_t)(bloc*512)*H + cc*4;
    #pragma unroll 8
    for (int tt = 0; tt < 512; tt++){
      s4v hv = *(const s4v*)(hp + (size_t)tt*H);
      float wv = wdyn[tt][hh4];
      agg[0] += wv * bf2f((u16)hv[0]);
      agg[1] += wv * bf2f((u16)hv[1]);
      agg[2] += wv * bf2f((u16)hv[2]);
      agg[3] += wv * bf2f((u16)hv[3]);
    }
    #pragma unroll
    for (int e2 = 0; e2 < 8; e2++){
      s4v hv = *(const s4v*)(h + (size_t)(ctext + bloc*8 + e2)*H + cc*4);
      float wv = sw[e2][hh4];
      agg[0] += wv * bf2f((u16)hv[0]);
      agg[1] += wv * bf2f((u16)hv[1]);
      agg[2] += wv * bf2f((u16)hv[2]);
      agg[3] += wv * bf2f((u16)hv[3]);
    }
  }
  float y[4] = {0.f,0.f,0.f,0.f};
  float sum = 0.f, sumsq = 0.f;
  if (cc < 192){
    s4v bv = *(const s4v*)(bias + cc*4);
    s4v xv = *(const s4v*)(xs_c + (size_t)idx*H + cc*4);
    #pragma unroll
    for (int c = 0; c < 4; c++){
      float a = agg[c] * dinv;
      float o = fmaxf(a + bf2f((u16)bv[c]), 0.f);
      float yv = o + bf2f((u16)xv[c]);
      y[c] = yv; sum += yv; sumsq += yv*yv;
    }
  }
  for (int o = 32; o > 0; o >>= 1){ sum += __shfl_down(sum, o); sumsq += __shfl_down(sumsq, o); }
  if (lane == 0){ wred[wave] = sum; wred[8 + wave] = sumsq; }
  __syncthreads();
  sum   = wred[0] + wred[1] + wred[2] + wred[3];
  sumsq = wred[8] + wred[9] + wred[10] + wred[11];
  float mean = sum * (1.f/H);
  float var = sumsq * (1.f/H) - mean*mean;
  float rstd = rsqrtf(fmaxf(var, 0.f) + 1e-5f);
  if (cc < 192){
    s4v gv = *(const s4v*)(gamma + cc*4);
    s4v bev = *(const s4v*)(beta + cc*4);
    s4v wv;
    #pragma unroll
    for (int c = 0; c < 4; c++){
      float o = (y[c] - mean) * rstd * bf2f((u16)gv[c]) + bf2f((u16)bev[c]);
      wv[c] = (short)f2bf(o);
    }
    *(s4v*)(xs_c + (size_t)idx*H + cc*4) = wv;
  }
}

extern "C" void kernel_launch(void* const* d_in, const int* in_sizes, int n_in,
                              void* d_out, int out_size, void* d_ws, size_t ws_size,
                              hipStream_t stream){
  const void* text  = d_in[0];
  const void* label = d_in[1];
  const void* image = d_in[2];

  auto align256 = [](size_t x){ return (x + 255) & ~(size_t)255; };
  auto baseNeed = [&](int cand) -> size_t {
    int ct = MTEXT/cand, cs = MSPEC/cand;
    int st = (cs + 127)/128;
    size_t hr = (size_t)ct + (size_t)st*128;
    return align256(4)
         + align256(hr*H*2)
         + align256((size_t)(MSPEC+64)*H*2)
         + 2*align256((size_t)MTEXT*4)
         + align256((size_t)MSPEC*4)
         + 2*align256(hr*4*4)
         + align256((size_t)3*H*H*2)
         + 5*align256((size_t)3*H*2);
  };
  size_t bfExtra = 2*align256((size_t)MTEXT*H*2);   // xt_bf + xint

  // deterministic config from ws_size (graph-safe)
  int useBf = 0, nch = 8;
  for (int cand = 1; cand <= 8; cand <<= 1){
    if (baseNeed(cand) + bfExtra <= ws_size){ useBf = 1; nch = cand; break; }
  }
  if (!useBf){
    for (int cand = 1; cand <= 8; cand <<= 1){
      if (baseNeed(cand) <= ws_size || cand == 8){ nch = cand; break; }
    }
  }
  int ctext = MTEXT/nch, cspec = MSPEC/nch;
  int spec_tiles = (cspec + 127)/128;
  int hrows = ctext + spec_tiles*128;
  int text_tiles = ctext / 128;

  char* ws = (char*)d_ws;
  size_t off = 0;
  auto alloc = [&](size_t bytes) -> void* {
    void* p = ws + off; off += (bytes + 255) & ~(size_t)255; return p;
  };
  int*   flag = (int*)  alloc(4);
  u16*   h    = (u16*)  alloc((size_t)hrows*H*2);
  u16*   xs   = (u16*)  alloc((size_t)(MSPEC+64)*H*2);
  int*   exl  = (int*)  alloc((size_t)MTEXT*4);
  int*   exi  = (int*)  alloc((size_t)MTEXT*4);
  float* nrm  = (float*)alloc((size_t)MSPEC*4);
  float* es   = (float*)alloc((size_t)hrows*4*4);
  float* ed   = (float*)alloc((size_t)hrows*4*4);
  u16*   Wc   = (u16*)  alloc((size_t)3*H*H*2);
  u16*   asc  = (u16*)  alloc((size_t)3*H*2);
  u16*   adc  = (u16*)  alloc((size_t)3*H*2);
  u16*   bc   = (u16*)  alloc((size_t)3*H*2);
  u16*   gc   = (u16*)  alloc((size_t)3*H*2);
  u16*   bec  = (u16*)  alloc((size_t)3*H*2);
  u16*   xt_bf = nullptr;
  u16*   xint  = nullptr;
  if (useBf){
    xt_bf = (u16*)alloc((size_t)MTEXT*H*2);
    xint  = (u16*)alloc((size_t)MTEXT*H*2);
  }

  detect_kernel<<<1, 256, 0, stream>>>((const u16*)text, flag);
  convert_kernel<<<(3*H*H + 255)/256, 256, 0, stream>>>(d_in[3], Wc, 3*H*H, flag);
  convert_kernel<<<9, 256, 0, stream>>>(d_in[4], asc, 3*H, flag);
  convert_kernel<<<9, 256, 0, stream>>>(d_in[5], adc, 3*H, flag);
  convert_kernel<<<9, 256, 0, stream>>>(d_in[6], bc,  3*H, flag);
  convert_kernel<<<9, 256, 0, stream>>>(d_in[7], gc,  3*H, flag);
  convert_kernel<<<9, 256, 0, stream>>>(d_in[8], bec, 3*H, flag);

  prep_spec_kernel<<<MSPEC, 256, 0, stream>>>(label, image, xs, nrm, flag);
  topk_kernel<<<dim3(T/16, B), 256, 0, stream>>>(text, label, image, nrm, exl, exi, flag);
  if (useBf)
    convert_text_kernel<<<(MTEXT*H/4 + 255)/256, 256, 0, stream>>>(text, xt_bf, flag);

  for (int l = 0; l < 3; l++){
    const void* At; int forceBf;
    if (useBf){ At = (l == 0) ? (const void*)xt_bf : (const void*)xint; forceBf = 1; }
    else      { At = (l == 0) ? text : (const void*)d_out;              forceBf = 0; }
    const u16* xres = useBf ? ((l == 0) ? xt_bf : xint) : nullptr;
    const void* xraw = (l == 0) ? text : (const void*)d_out;
    int outRaw = (!useBf) || (l == 2);

    for (int c = 0; c < nch; c++){
      gemm_kernel<<<(text_tiles + spec_tiles)*6, 256, 0, stream>>>(
          At, c*ctext, xs + (size_t)c*cspec*H, Wc + (size_t)l*H*H, h,
          text_tiles, ctext, forceBf, flag);
      node_att_kernel<<<(ctext + cspec + 3)/4, 256, 0, stream>>>(
          h, asc + l*H, adc + l*H, es, ed, ctext + cspec);
      attn_spec_kernel<<<cspec, 256, 0, stream>>>(
          h, xs + (size_t)c*cspec*H, es, ed,
          exl + c*ctext, exi + c*ctext,
          bc + l*H, gc + l*H, bec + l*H, ctext);
      attn_text_kernel<<<ctext/4, 256, 0, stream>>>(
          h, xres, xraw, c*ctext, d_out, xint,
          es, ed, exl + c*ctext, exi + c*ctext,
          bc + l*H, gc + l*H, bec + l*H,
          ctext, useBf, outRaw, flag);
    }
  }
}